// Round 7
// baseline (2518.008 us; speedup 1.0000x reference)
//
#include <hip/hip_runtime.h>
#include <hip/hip_bf16.h>

// Problem constants (reference: N=8192, D=H=1024, NSTEP=8)
#define NN 8192
#define HH 1024
#define NSTEP 8
#define NBLK 256
#define NTHR 512
#define PSTR 1040   // partial-slot stride in floats {l, pad7, ctx[1024], pad8}

// ---- workspace layout (float offsets) ----
#define OFF_ATTN   0                     // attn_feat [8192*1024]
#define OFF_HOP    8388608               // hop_feat  [8192*1024]
#define B2         16777216
#define OFF_NEG    (B2 + 0)              // [8192]
#define OFF_SEL    (B2 + 8192)           // [8192]
#define OFF_H      (B2 + 16384)          // h[parity][chain][1024]
#define OFF_C      (B2 + 20480)          // c[parity][chain][1024]
#define OFF_QW     (B2 + 24576)          // qw[chain][1024]
#define OFF_QW2    (B2 + 26624)          // qw2[chain][1024]
#define OFF_Q      (B2 + 28672)          // combined glimpse q [chain][1024]
#define OFF_XC     (B2 + 30720)          // combined critic attn ctx [1024]
#define OFF_AMAX   (B2 + 31744)          // packed u64 argmax (8B aligned)
#define OFF_BAR    (B2 + 31760)          // barrier counter (uint), own cacheline
#define OFF_GPA    (B2 + 32768)          // glimpse partials actor  [256][PSTR]
#define OFF_GPC    (OFF_GPA + 256*PSTR)  // glimpse partials critic [256][PSTR]
#define OFF_APC    (OFF_GPC + 256*PSTR)  // attn critic partials    [256][PSTR]

__device__ __forceinline__ float sigmoidf_(float x) {
    return 1.0f / (1.0f + __expf(-x));
}
__device__ __forceinline__ float tanhf_(float x) {
    float e = __expf(2.0f * x);
    return 1.0f - 2.0f / (e + 1.0f);
}

__device__ __forceinline__ float score16(const float4* f, const float4* q, const float4* v) {
    float s = 0.0f;
#pragma unroll
    for (int j = 0; j < 4; j++) {
        s += tanhf_(f[j].x + q[j].x) * v[j].x;
        s += tanhf_(f[j].y + q[j].y) * v[j].y;
        s += tanhf_(f[j].z + q[j].z) * v[j].z;
        s += tanhf_(f[j].w + q[j].w) * v[j].w;
    }
    return s;
}

// software grid barrier: release arrival, relaxed spin, one acquire fence on exit
__device__ __forceinline__ void gsync(unsigned int* bar, unsigned int target) {
    __syncthreads();
    if (threadIdx.x == 0) {
        __hip_atomic_fetch_add(bar, 1u, __ATOMIC_RELEASE, __HIP_MEMORY_SCOPE_AGENT);
        while (__hip_atomic_load(bar, __ATOMIC_RELAXED, __HIP_MEMORY_SCOPE_AGENT) < target)
            __builtin_amdgcn_s_sleep(2);
    }
    __syncthreads();
    __builtin_amdgcn_fence(__ATOMIC_ACQUIRE, "agent");
}

// monotone orderable key for fp32 + first-index tie-break
__device__ __forceinline__ unsigned long long packscore(float f, int i) {
    unsigned int u = __float_as_uint(f);
    unsigned int key = (u & 0x80000000u) ? ~u : (u | 0x80000000u);
    return ((unsigned long long)key << 32) | (unsigned int)(0x7FFFFFFF - i);
}

// ---------------- GEMM: feats = enc @ {attn_wm, hop_wm}, 128x128 tile, 8x8/thread ----------------
__global__ __launch_bounds__(256, 4) void k_gemm(const float* __restrict__ A,
                                                 const float* __restrict__ W0,
                                                 const float* __restrict__ W1,
                                                 float* __restrict__ ws) {
    const float* B = blockIdx.z ? W1 : W0;
    float* Cout = ws + (blockIdx.z ? OFF_HOP : OFF_ATTN);
    const int rowbase = blockIdx.y * 128;
    const int colbase = blockIdx.x * 128;
    __shared__ float As[16][132];
    __shared__ float Bs[16][132];
    const int t  = threadIdx.x;
    const int tx = t & 15;
    const int ty2 = t >> 4;  // 0..15
    const int ar = t >> 1, aks = (t & 1) * 8;
    const int bk = t >> 4, bc = (t & 15) * 8;
    float acc[8][8] = {};
    for (int kk = 0; kk < 1024; kk += 16) {
        float4 a0 = *(const float4*)&A[(size_t)(rowbase + ar) * 1024 + kk + aks];
        float4 a1 = *(const float4*)&A[(size_t)(rowbase + ar) * 1024 + kk + aks + 4];
        float4 b0 = *(const float4*)&B[(size_t)(kk + bk) * 1024 + colbase + bc];
        float4 b1 = *(const float4*)&B[(size_t)(kk + bk) * 1024 + colbase + bc + 4];
        __syncthreads();
        As[aks + 0][ar] = a0.x; As[aks + 1][ar] = a0.y;
        As[aks + 2][ar] = a0.z; As[aks + 3][ar] = a0.w;
        As[aks + 4][ar] = a1.x; As[aks + 5][ar] = a1.y;
        As[aks + 6][ar] = a1.z; As[aks + 7][ar] = a1.w;
        *(float4*)&Bs[bk][bc]     = b0;
        *(float4*)&Bs[bk][bc + 4] = b1;
        __syncthreads();
#pragma unroll
        for (int k = 0; k < 16; k++) {
            float4 x0 = *(const float4*)&As[k][ty2 * 4];
            float4 x1 = *(const float4*)&As[k][ty2 * 4 + 64];
            float4 y0 = *(const float4*)&Bs[k][tx * 4];
            float4 y1 = *(const float4*)&Bs[k][tx * 4 + 64];
            float xa[8] = {x0.x, x0.y, x0.z, x0.w, x1.x, x1.y, x1.z, x1.w};
            float yb[8] = {y0.x, y0.y, y0.z, y0.w, y1.x, y1.y, y1.z, y1.w};
#pragma unroll
            for (int i = 0; i < 8; i++)
#pragma unroll
                for (int j = 0; j < 8; j++)
                    acc[i][j] += xa[i] * yb[j];
        }
    }
#pragma unroll
    for (int i = 0; i < 8; i++) {
        int row = rowbase + ((i < 4) ? (ty2 * 4 + i) : (64 + ty2 * 4 + (i - 4)));
        float* cr = &Cout[(size_t)row * 1024 + colbase];
        *(float4*)&cr[tx * 4]      = make_float4(acc[i][0], acc[i][1], acc[i][2], acc[i][3]);
        *(float4*)&cr[64 + tx * 4] = make_float4(acc[i][4], acc[i][5], acc[i][6], acc[i][7]);
    }
}

// ---------------- persistent fused 8-step decode ----------------
// grid 256 x block 512, 1 block/CU; lane chunk mapping: cols {lane*4 + p*256}
__global__ __launch_bounds__(512) void k_steps(
        const float* __restrict__ enc, const int* __restrict__ mask,
        const float* __restrict__ attn_wq, const float* __restrict__ attn_v,
        const float* __restrict__ hop_wq, const float* __restrict__ hop_v,
        const float* __restrict__ init_h, const float* __restrict__ init_c,
        const float* __restrict__ init_i,
        const float* __restrict__ w_ih, const float* __restrict__ w_hh,
        const float* __restrict__ b_ih, const float* __restrict__ b_hh,
        const float* __restrict__ score_w, const float* __restrict__ score_b,
        float* __restrict__ ws, float* __restrict__ out) {
    const int b = blockIdx.x;
    const int t = threadIdx.x;
    const int w = t >> 6, lane = t & 63;
    __shared__ __align__(16) float smem[8224];
    unsigned int* bar = (unsigned int*)(ws + OFF_BAR);
    unsigned int bt = 0;

    // ---- phase 0: init ----
    {
        int i = b * NTHR + t;
        if (i < NN) {
            ws[OFF_NEG + i] = (mask[i] == 0) ? -1e8f : 0.0f;
            ws[OFF_SEL + i] = 0.0f;
        }
        if (i < 2048) {  // parity-0 h,c for both chains
            ws[OFF_H + i] = init_h[i & 1023];
            ws[OFF_C + i] = init_c[i & 1023];
        }
        if (b == 16 && t == 0) *(unsigned long long*)&ws[OFF_AMAX] = 0ull;
    }
    bt += NBLK; gsync(bar, bt);

    for (int step = 0; step < NSTEP; step++) {
        const int par = step & 1;
        // ===== P1: finalize prev step (block 0) + LSTM both chains =====
        {
            int besti = 0;
            if (step > 0) {
                unsigned long long pk = *(const unsigned long long*)&ws[OFF_AMAX];
                besti = 0x7FFFFFFF - (int)(unsigned int)(pk & 0xFFFFFFFFull);
            }
            if (step > 0 && b == 0) {
                float p = ws[OFF_XC + t] * score_w[t]
                        + ws[OFF_XC + t + 512] * score_w[t + 512];
#pragma unroll
                for (int off = 32; off; off >>= 1) p += __shfl_down(p, off);
                if (lane == 0) smem[8192 + w] = p;
                __syncthreads();
                if (t == 0) {
                    float s = 0.0f;
#pragma unroll
                    for (int ww = 0; ww < 8; ww++) s += smem[8192 + ww];
                    out[8 + NSTEP * 1024 + (step - 1)] = s + score_b[0];
                    out[step - 1] = (float)besti;
                    ws[OFF_SEL + besti] = -1e18f;
                }
                __syncthreads();
            }
            const int j = b * 8 + w;  // 2048 waves, j < 1024 guard
            if (j < 1024) {
                float4 xa[4], xc[4], ha[4], hc[4];
#pragma unroll
                for (int p = 0; p < 4; p++) {
                    int kk = lane * 4 + p * 256;
                    if (step == 0) {
                        xa[p] = *(const float4*)&init_i[kk];
                        xc[p] = xa[p];
                    } else {
                        xa[p] = *(const float4*)&enc[(size_t)besti * 1024 + kk];
                        xc[p] = *(const float4*)&ws[OFF_XC + kk];
                    }
                    ha[p] = *(const float4*)&ws[OFF_H + par * 2048 + kk];
                    hc[p] = *(const float4*)&ws[OFF_H + par * 2048 + 1024 + kk];
                }
                float pa[4], pc[4];
#pragma unroll
                for (int g = 0; g < 4; g++) {
                    const float* wi = w_ih + (size_t)(g * 1024 + j) * 1024;
                    const float* wh = w_hh + (size_t)(g * 1024 + j) * 1024;
                    float sa = 0.0f, sc = 0.0f;
#pragma unroll
                    for (int p = 0; p < 4; p++) {
                        int kk = lane * 4 + p * 256;
                        float4 a = *(const float4*)&wi[kk];
                        float4 hh = *(const float4*)&wh[kk];
                        sa += a.x * xa[p].x + a.y * xa[p].y + a.z * xa[p].z + a.w * xa[p].w
                            + hh.x * ha[p].x + hh.y * ha[p].y + hh.z * ha[p].z + hh.w * ha[p].w;
                        sc += a.x * xc[p].x + a.y * xc[p].y + a.z * xc[p].z + a.w * xc[p].w
                            + hh.x * hc[p].x + hh.y * hc[p].y + hh.z * hc[p].z + hh.w * hc[p].w;
                    }
                    pa[g] = sa; pc[g] = sc;
                }
#pragma unroll
                for (int off = 1; off < 64; off <<= 1) {
#pragma unroll
                    for (int g = 0; g < 4; g++) {
                        pa[g] += __shfl_xor(pa[g], off);
                        pc[g] += __shfl_xor(pc[g], off);
                    }
                }
                if (lane == 0) {
                    float bb0 = b_ih[j] + b_hh[j];
                    float bb1 = b_ih[1024 + j] + b_hh[1024 + j];
                    float bb2 = b_ih[2048 + j] + b_hh[2048 + j];
                    float bb3 = b_ih[3072 + j] + b_hh[3072 + j];
                    {
                        float ig = sigmoidf_(pa[0] + bb0), fg = sigmoidf_(pa[1] + bb1);
                        float gg = tanhf_(pa[2] + bb2),   og = sigmoidf_(pa[3] + bb3);
                        float cv = fg * ws[OFF_C + par * 2048 + j] + ig * gg;
                        ws[OFF_H + (par ^ 1) * 2048 + j] = og * tanhf_(cv);
                        ws[OFF_C + (par ^ 1) * 2048 + j] = cv;
                    }
                    {
                        float ig = sigmoidf_(pc[0] + bb0), fg = sigmoidf_(pc[1] + bb1);
                        float gg = tanhf_(pc[2] + bb2),   og = sigmoidf_(pc[3] + bb3);
                        float cv = fg * ws[OFF_C + par * 2048 + 1024 + j] + ig * gg;
                        ws[OFF_H + (par ^ 1) * 2048 + 1024 + j] = og * tanhf_(cv);
                        ws[OFF_C + (par ^ 1) * 2048 + 1024 + j] = cv;
                    }
                }
            }
        }
        bt += NBLK; gsync(bar, bt);

        // ===== P2: qw = h' @ hop_wq (blocks 0..31); block 32 resets AMAX =====
        if (b < 32) {
            const int chain = b >> 4, kb = b & 15;
            const float* hsrc = ws + OFF_H + (par ^ 1) * 2048 + chain * 1024;
            smem[t]       = hsrc[t];
            smem[t + 512] = hsrc[t + 512];
            __syncthreads();
            const int col = kb * 64 + (t & 63);
            const int jg = t >> 6;
            const float* wq = hop_wq + (size_t)jg * 128 * 1024 + col;
            float acc = 0.0f;
#pragma unroll 8
            for (int j = 0; j < 128; j++) acc += smem[jg * 128 + j] * wq[(size_t)j * 1024];
            __syncthreads();
            smem[1024 + t] = acc;
            __syncthreads();
            if (t < 64) {
                float s = 0.0f;
#pragma unroll
                for (int jg2 = 0; jg2 < 8; jg2++) s += smem[1024 + jg2 * 64 + t];
                ws[OFF_QW + chain * 1024 + kb * 64 + t] = s;
            }
        } else if (b == 32 && t == 0) {
            *(unsigned long long*)&ws[OFF_AMAX] = 0ull;
        }
        bt += NBLK; gsync(bar, bt);

        // ===== P3: glimpse scan over hop_feat (both chains) -> per-block partials =====
        {
            float4 qa[4], qc[4], v4[4];
#pragma unroll
            for (int p = 0; p < 4; p++) {
                int kk = lane * 4 + p * 256;
                qa[p] = *(const float4*)&ws[OFF_QW + kk];
                qc[p] = *(const float4*)&ws[OFF_QW + 1024 + kk];
                v4[p] = *(const float4*)&hop_v[kk];
            }
            float la = 0.0f, lc = 0.0f;
            float4 ca[4] = {}, cc[4] = {};
            for (int i = b * 8 + w; i < NN; i += 2048) {
                const float* row = ws + OFF_HOP + (size_t)i * 1024;
                float4 f[4];
#pragma unroll
                for (int p = 0; p < 4; p++) f[p] = *(const float4*)&row[lane * 4 + p * 256];
                float sa = score16(f, qa, v4);
                float sc = score16(f, qc, v4);
#pragma unroll
                for (int off = 1; off < 64; off <<= 1) {
                    sa += __shfl_xor(sa, off);
                    sc += __shfl_xor(sc, off);
                }
                float ng = ws[OFF_NEG + i];
                float ea = __expf(sa + ng), ec = __expf(sc + ng);
                la += ea; lc += ec;
#pragma unroll
                for (int p = 0; p < 4; p++) {
                    ca[p].x += ea * f[p].x; ca[p].y += ea * f[p].y;
                    ca[p].z += ea * f[p].z; ca[p].w += ea * f[p].w;
                    cc[p].x += ec * f[p].x; cc[p].y += ec * f[p].y;
                    cc[p].z += ec * f[p].z; cc[p].w += ec * f[p].w;
                }
            }
            // block-combine across 8 waves, then plain stores to partial slot
            float* gpa = ws + OFF_GPA + (size_t)b * PSTR;
            float* gpc = ws + OFF_GPC + (size_t)b * PSTR;
            // actor
            if (lane == 0) smem[8192 + w] = la;
#pragma unroll
            for (int p = 0; p < 4; p++) *(float4*)&smem[w * 1024 + lane * 4 + p * 256] = ca[p];
            __syncthreads();
            {
                const int k = t * 2;
                float s0 = 0.0f, s1 = 0.0f;
#pragma unroll
                for (int ww = 0; ww < 8; ww++) {
                    s0 += smem[ww * 1024 + k];
                    s1 += smem[ww * 1024 + k + 1];
                }
                gpa[8 + k] = s0; gpa[8 + k + 1] = s1;
                if (t == 0) {
                    float s = 0.0f;
#pragma unroll
                    for (int ww = 0; ww < 8; ww++) s += smem[8192 + ww];
                    gpa[0] = s;
                }
            }
            __syncthreads();
            // critic
            if (lane == 0) smem[8192 + w] = lc;
#pragma unroll
            for (int p = 0; p < 4; p++) *(float4*)&smem[w * 1024 + lane * 4 + p * 256] = cc[p];
            __syncthreads();
            {
                const int k = t * 2;
                float s0 = 0.0f, s1 = 0.0f;
#pragma unroll
                for (int ww = 0; ww < 8; ww++) {
                    s0 += smem[ww * 1024 + k];
                    s1 += smem[ww * 1024 + k + 1];
                }
                gpc[8 + k] = s0; gpc[8 + k + 1] = s1;
                if (t == 0) {
                    float s = 0.0f;
#pragma unroll
                    for (int ww = 0; ww < 8; ww++) s += smem[8192 + ww];
                    gpc[0] = s;
                }
            }
            __syncthreads();
        }
        bt += NBLK; gsync(bar, bt);

        // ===== P4: combine q = sum(ctx)/sum(l), both chains (256 blocks x 8 cols) =====
        {
            const int chain = b >> 7;
            const int base = (b & 127) * 8;
            const float* gp = ws + (chain ? OFF_GPC : OFF_GPA);
            if (t < 64) {  // wave 0: reduce the 256 l-partials
                float l = gp[(size_t)t * PSTR] + gp[(size_t)(t + 64) * PSTR]
                        + gp[(size_t)(t + 128) * PSTR] + gp[(size_t)(t + 192) * PSTR];
#pragma unroll
                for (int off = 1; off < 64; off <<= 1) l += __shfl_xor(l, off);
                if (t == 0) smem[600] = l;
            }
            const int col = base + (t & 7);
            const int p0 = t >> 3;  // 64 partial groups
            float s = gp[(size_t)p0 * PSTR + 8 + col]
                    + gp[(size_t)(p0 + 64) * PSTR + 8 + col]
                    + gp[(size_t)(p0 + 128) * PSTR + 8 + col]
                    + gp[(size_t)(p0 + 192) * PSTR + 8 + col];
            smem[t] = s;
            __syncthreads();
            for (int off = 256; off >= 8; off >>= 1) {
                if (t < off) smem[t] += smem[t + off];
                __syncthreads();
            }
            if (t < 8) {
                float q = smem[t] / smem[600];
                ws[OFF_Q + chain * 1024 + base + t] = q;
                if (chain == 0) out[8 + step * 1024 + base + t] = q;
            }
        }
        bt += NBLK; gsync(bar, bt);

        // ===== P5: qw2 = q @ attn_wq (blocks 0..31) =====
        if (b < 32) {
            const int chain = b >> 4, kb = b & 15;
            const float* qsrc = ws + OFF_Q + chain * 1024;
            smem[t]       = qsrc[t];
            smem[t + 512] = qsrc[t + 512];
            __syncthreads();
            const int col = kb * 64 + (t & 63);
            const int jg = t >> 6;
            const float* aw = attn_wq + (size_t)jg * 128 * 1024 + col;
            float acc = 0.0f;
#pragma unroll 8
            for (int j = 0; j < 128; j++) acc += smem[jg * 128 + j] * aw[(size_t)j * 1024];
            __syncthreads();
            smem[1024 + t] = acc;
            __syncthreads();
            if (t < 64) {
                float s = 0.0f;
#pragma unroll
                for (int jg2 = 0; jg2 < 8; jg2++) s += smem[1024 + jg2 * 64 + t];
                ws[OFF_QW2 + chain * 1024 + kb * 64 + t] = s;
            }
        }
        bt += NBLK; gsync(bar, bt);

        // ===== P6: attn scan — actor argmax (u64 atomicMax) + critic partials over enc =====
        {
            float4 qa[4], qc[4], v4[4];
#pragma unroll
            for (int p = 0; p < 4; p++) {
                int kk = lane * 4 + p * 256;
                qa[p] = *(const float4*)&ws[OFF_QW2 + kk];
                qc[p] = *(const float4*)&ws[OFF_QW2 + 1024 + kk];
                v4[p] = *(const float4*)&attn_v[kk];
            }
            float bm = -1e30f;
            int bi = 0;
            float lc = 0.0f;
            float4 cc[4] = {};
            for (int i = b * 8 + w; i < NN; i += 2048) {
                const float* frow = ws + OFF_ATTN + (size_t)i * 1024;
                const float* erow = enc + (size_t)i * 1024;
                float4 f[4], e[4];
#pragma unroll
                for (int p = 0; p < 4; p++) {
                    f[p] = *(const float4*)&frow[lane * 4 + p * 256];
                    e[p] = *(const float4*)&erow[lane * 4 + p * 256];
                }
                float sa = score16(f, qa, v4);
                float sc = score16(f, qc, v4);
#pragma unroll
                for (int off = 1; off < 64; off <<= 1) {
                    sa += __shfl_xor(sa, off);
                    sc += __shfl_xor(sc, off);
                }
                float ng = ws[OFF_NEG + i];
                float Sa = sa + ng + ws[OFF_SEL + i];
                if (Sa > bm) { bm = Sa; bi = i; }
                float ec = __expf(sc + ng);
                lc += ec;
#pragma unroll
                for (int p = 0; p < 4; p++) {
                    cc[p].x += ec * e[p].x; cc[p].y += ec * e[p].y;
                    cc[p].z += ec * e[p].z; cc[p].w += ec * e[p].w;
                }
            }
            unsigned long long* spk = (unsigned long long*)(smem + 8200);
            if (lane == 0) { smem[8192 + w] = lc; spk[w] = packscore(bm, bi); }
#pragma unroll
            for (int p = 0; p < 4; p++) *(float4*)&smem[w * 1024 + lane * 4 + p * 256] = cc[p];
            __syncthreads();
            float* apc = ws + OFF_APC + (size_t)b * PSTR;
            {
                const int k = t * 2;
                float s0 = 0.0f, s1 = 0.0f;
#pragma unroll
                for (int ww = 0; ww < 8; ww++) {
                    s0 += smem[ww * 1024 + k];
                    s1 += smem[ww * 1024 + k + 1];
                }
                apc[8 + k] = s0; apc[8 + k + 1] = s1;
                if (t == 0) {
                    float s = 0.0f;
                    unsigned long long mx = 0ull;
#pragma unroll
                    for (int ww = 0; ww < 8; ww++) {
                        s += smem[8192 + ww];
                        if (spk[ww] > mx) mx = spk[ww];
                    }
                    apc[0] = s;
                    atomicMax((unsigned long long*)&ws[OFF_AMAX], mx);
                }
            }
            __syncthreads();
        }
        bt += NBLK; gsync(bar, bt);

        // ===== P7: combine critic ctx -> XC (256 blocks x 4 cols) =====
        {
            const float* ap = ws + OFF_APC;
            if (t < 64) {
                float l = ap[(size_t)t * PSTR] + ap[(size_t)(t + 64) * PSTR]
                        + ap[(size_t)(t + 128) * PSTR] + ap[(size_t)(t + 192) * PSTR];
#pragma unroll
                for (int off = 1; off < 64; off <<= 1) l += __shfl_xor(l, off);
                if (t == 0) smem[600] = l;
            }
            const int col = b * 4 + (t & 3);
            const int p0 = t >> 2;  // 128 partial groups
            float s = ap[(size_t)p0 * PSTR + 8 + col]
                    + ap[(size_t)(p0 + 128) * PSTR + 8 + col];
            smem[t] = s;
            __syncthreads();
            for (int off = 256; off >= 4; off >>= 1) {
                if (t < off) smem[t] += smem[t + off];
                __syncthreads();
            }
            if (t < 4) ws[OFF_XC + b * 4 + t] = smem[t] / smem[600];
        }
        bt += NBLK; gsync(bar, bt);
    }

    // ===== epilogue: finalize step 7 (block 0) =====
    if (b == 0) {
        unsigned long long pk = *(const unsigned long long*)&ws[OFF_AMAX];
        int besti = 0x7FFFFFFF - (int)(unsigned int)(pk & 0xFFFFFFFFull);
        float p = ws[OFF_XC + t] * score_w[t]
                + ws[OFF_XC + t + 512] * score_w[t + 512];
#pragma unroll
        for (int off = 32; off; off >>= 1) p += __shfl_down(p, off);
        if (lane == 0) smem[8192 + w] = p;
        __syncthreads();
        if (t == 0) {
            float s = 0.0f;
#pragma unroll
            for (int ww = 0; ww < 8; ww++) s += smem[8192 + ww];
            out[8 + NSTEP * 1024 + (NSTEP - 1)] = s + score_b[0];
            out[NSTEP - 1] = (float)besti;
        }
    }
}

extern "C" void kernel_launch(void* const* d_in, const int* in_sizes, int n_in,
                              void* d_out, int out_size, void* d_ws, size_t ws_size,
                              hipStream_t stream) {
    const float* enc     = (const float*)d_in[0];
    const int*   mask    = (const int*)d_in[1];
    const float* attn_wm = (const float*)d_in[2];
    const float* attn_wq = (const float*)d_in[3];
    const float* attn_v  = (const float*)d_in[4];
    const float* hop_wm  = (const float*)d_in[5];
    const float* hop_wq  = (const float*)d_in[6];
    const float* hop_v   = (const float*)d_in[7];
    const float* init_i  = (const float*)d_in[8];
    const float* init_h  = (const float*)d_in[9];
    const float* init_c  = (const float*)d_in[10];
    const float* w_ih    = (const float*)d_in[11];
    const float* w_hh    = (const float*)d_in[12];
    const float* b_ih    = (const float*)d_in[13];
    const float* b_hh    = (const float*)d_in[14];
    const float* score_w = (const float*)d_in[15];
    const float* score_b = (const float*)d_in[16];
    float* ws  = (float*)d_ws;
    float* out = (float*)d_out;

    // zero the software grid-barrier counter (graph-capturable async memset)
    (void)hipMemsetAsync((char*)d_ws + (size_t)OFF_BAR * sizeof(float), 0, 64, stream);

    k_gemm<<<dim3(8, 64, 2), 256, 0, stream>>>(enc, attn_wm, hop_wm, ws);

    k_steps<<<NBLK, NTHR, 0, stream>>>(enc, mask, attn_wq, attn_v, hop_wq, hop_v,
                                       init_h, init_c, init_i, w_ih, w_hh, b_ih,
                                       b_hh, score_w, score_b, ws, out);
}

// Round 8
// 2119.318 us; speedup vs baseline: 1.1881x; 1.1881x over previous
//
#include <hip/hip_runtime.h>
#include <hip/hip_bf16.h>

// Problem constants (reference: N=8192, D=H=1024, NSTEP=8)
#define NN 8192
#define HH 1024
#define NSTEP 8
#define NBLK 256
#define NTHR 512
#define PSTR 1040   // partial-slot stride in floats {l, pad7, ctx[1024], pad8}

// ---- workspace layout (float offsets) ----
#define OFF_ATTN   0                     // attn_feat [8192*1024]
#define OFF_HOP    8388608               // hop_feat  [8192*1024]
#define B2         16777216
#define OFF_NEG    (B2 + 0)              // [8192]
#define OFF_SEL    (B2 + 8192)           // [8192]
#define OFF_H      (B2 + 16384)          // h[parity][chain][1024]
#define OFF_C      (B2 + 20480)          // c[parity][chain][1024]
#define OFF_QW     (B2 + 24576)          // qw[chain][1024]
#define OFF_QW2    (B2 + 26624)          // qw2[chain][1024]
#define OFF_Q      (B2 + 28672)          // combined glimpse q [chain][1024]
#define OFF_XC     (B2 + 30720)          // combined critic attn ctx [1024]
#define OFF_AMAX   (B2 + 31744)          // packed u64 argmax (8B aligned)
// hierarchical barrier block (zeroed via hipMemsetAsync): 2048 floats
#define OFF_GO     (B2 + 32768)          // go epoch word
#define OFF_MASTER (B2 + 32832)          // master counter (own 256B line)
#define OFF_GRP    (B2 + 32896)          // 16 group counters, stride 64 floats
#define OFF_GPA    (B2 + 34816)          // glimpse partials actor  [256][PSTR]
#define OFF_GPC    (OFF_GPA + 256*PSTR)  // glimpse partials critic [256][PSTR]
#define OFF_APC    (OFF_GPC + 256*PSTR)  // attn critic partials    [256][PSTR]

__device__ __forceinline__ float sigmoidf_(float x) {
    return 1.0f / (1.0f + __expf(-x));
}
__device__ __forceinline__ float tanhf_(float x) {
    float e = __expf(2.0f * x);
    return 1.0f - 2.0f / (e + 1.0f);
}

__device__ __forceinline__ float score16(const float4* f, const float4* q, const float4* v) {
    float s = 0.0f;
#pragma unroll
    for (int j = 0; j < 4; j++) {
        s += tanhf_(f[j].x + q[j].x) * v[j].x;
        s += tanhf_(f[j].y + q[j].y) * v[j].y;
        s += tanhf_(f[j].z + q[j].z) * v[j].z;
        s += tanhf_(f[j].w + q[j].w) * v[j].w;
    }
    return s;
}

// hierarchical epoch barrier: 16 groups x 16 blocks -> master -> go word.
// Arrival RMWs spread over 17 lines; spinners poll ONE clean line at ~1k-cycle
// intervals (low LLC bank pressure). e is the 1-based barrier epoch.
__device__ __forceinline__ void gsync(float* ws, unsigned int e) {
    __syncthreads();
    if (threadIdx.x == 0) {
        unsigned int* go     = (unsigned int*)(ws + OFF_GO);
        unsigned int* master = (unsigned int*)(ws + OFF_MASTER);
        unsigned int* grp    = (unsigned int*)(ws + OFF_GRP + (blockIdx.x >> 4) * 64);
        unsigned int old = __hip_atomic_fetch_add(grp, 1u, __ATOMIC_RELEASE, __HIP_MEMORY_SCOPE_AGENT);
        if (old == e * 16u - 1u) {
            unsigned int om = __hip_atomic_fetch_add(master, 1u, __ATOMIC_ACQ_REL, __HIP_MEMORY_SCOPE_AGENT);
            if (om == e * 16u - 1u)
                __hip_atomic_store(go, e, __ATOMIC_RELEASE, __HIP_MEMORY_SCOPE_AGENT);
        }
        while (__hip_atomic_load(go, __ATOMIC_RELAXED, __HIP_MEMORY_SCOPE_AGENT) < e)
            __builtin_amdgcn_s_sleep(16);
    }
    __syncthreads();
    __builtin_amdgcn_fence(__ATOMIC_ACQUIRE, "agent");
}

// monotone orderable key for fp32 + first-index tie-break
__device__ __forceinline__ unsigned long long packscore(float f, int i) {
    unsigned int u = __float_as_uint(f);
    unsigned int key = (u & 0x80000000u) ? ~u : (u | 0x80000000u);
    return ((unsigned long long)key << 32) | (unsigned int)(0x7FFFFFFF - i);
}

// ---------------- GEMM: feats = enc @ {attn_wm, hop_wm}, 128x128 tile, 8x8/thread ----------------
__global__ __launch_bounds__(256, 4) void k_gemm(const float* __restrict__ A,
                                                 const float* __restrict__ W0,
                                                 const float* __restrict__ W1,
                                                 float* __restrict__ ws) {
    const float* B = blockIdx.z ? W1 : W0;
    float* Cout = ws + (blockIdx.z ? OFF_HOP : OFF_ATTN);
    const int rowbase = blockIdx.y * 128;
    const int colbase = blockIdx.x * 128;
    __shared__ float As[16][132];
    __shared__ float Bs[16][132];
    const int t  = threadIdx.x;
    const int tx = t & 15;
    const int ty2 = t >> 4;  // 0..15
    const int ar = t >> 1, aks = (t & 1) * 8;
    const int bk = t >> 4, bc = (t & 15) * 8;
    float acc[8][8] = {};
    for (int kk = 0; kk < 1024; kk += 16) {
        float4 a0 = *(const float4*)&A[(size_t)(rowbase + ar) * 1024 + kk + aks];
        float4 a1 = *(const float4*)&A[(size_t)(rowbase + ar) * 1024 + kk + aks + 4];
        float4 b0 = *(const float4*)&B[(size_t)(kk + bk) * 1024 + colbase + bc];
        float4 b1 = *(const float4*)&B[(size_t)(kk + bk) * 1024 + colbase + bc + 4];
        __syncthreads();
        As[aks + 0][ar] = a0.x; As[aks + 1][ar] = a0.y;
        As[aks + 2][ar] = a0.z; As[aks + 3][ar] = a0.w;
        As[aks + 4][ar] = a1.x; As[aks + 5][ar] = a1.y;
        As[aks + 6][ar] = a1.z; As[aks + 7][ar] = a1.w;
        *(float4*)&Bs[bk][bc]     = b0;
        *(float4*)&Bs[bk][bc + 4] = b1;
        __syncthreads();
#pragma unroll
        for (int k = 0; k < 16; k++) {
            float4 x0 = *(const float4*)&As[k][ty2 * 4];
            float4 x1 = *(const float4*)&As[k][ty2 * 4 + 64];
            float4 y0 = *(const float4*)&Bs[k][tx * 4];
            float4 y1 = *(const float4*)&Bs[k][tx * 4 + 64];
            float xa[8] = {x0.x, x0.y, x0.z, x0.w, x1.x, x1.y, x1.z, x1.w};
            float yb[8] = {y0.x, y0.y, y0.z, y0.w, y1.x, y1.y, y1.z, y1.w};
#pragma unroll
            for (int i = 0; i < 8; i++)
#pragma unroll
                for (int j = 0; j < 8; j++)
                    acc[i][j] += xa[i] * yb[j];
        }
    }
#pragma unroll
    for (int i = 0; i < 8; i++) {
        int row = rowbase + ((i < 4) ? (ty2 * 4 + i) : (64 + ty2 * 4 + (i - 4)));
        float* cr = &Cout[(size_t)row * 1024 + colbase];
        *(float4*)&cr[tx * 4]      = make_float4(acc[i][0], acc[i][1], acc[i][2], acc[i][3]);
        *(float4*)&cr[64 + tx * 4] = make_float4(acc[i][4], acc[i][5], acc[i][6], acc[i][7]);
    }
}

// ---------------- persistent fused 8-step decode ----------------
// grid 256 x block 512, 1 block/CU; lane chunk mapping: cols {lane*4 + p*256}
__global__ __launch_bounds__(512) void k_steps(
        const float* __restrict__ enc, const int* __restrict__ mask,
        const float* __restrict__ attn_wq, const float* __restrict__ attn_v,
        const float* __restrict__ hop_wq, const float* __restrict__ hop_v,
        const float* __restrict__ init_h, const float* __restrict__ init_c,
        const float* __restrict__ init_i,
        const float* __restrict__ w_ih, const float* __restrict__ w_hh,
        const float* __restrict__ b_ih, const float* __restrict__ b_hh,
        const float* __restrict__ score_w, const float* __restrict__ score_b,
        float* __restrict__ ws, float* __restrict__ out) {
    const int b = blockIdx.x;
    const int t = threadIdx.x;
    const int w = t >> 6, lane = t & 63;
    __shared__ __align__(16) float smem[8224];
    unsigned int bt = 0;

    // ---- phase 0: init ----
    {
        int i = b * NTHR + t;
        if (i < NN) {
            ws[OFF_NEG + i] = (mask[i] == 0) ? -1e8f : 0.0f;
            ws[OFF_SEL + i] = 0.0f;
        }
        if (i < 2048) {  // parity-0 h,c for both chains
            ws[OFF_H + i] = init_h[i & 1023];
            ws[OFF_C + i] = init_c[i & 1023];
        }
        if (b == 16 && t == 0) *(unsigned long long*)&ws[OFF_AMAX] = 0ull;
    }
    ++bt; gsync(ws, bt);

    for (int step = 0; step < NSTEP; step++) {
        const int par = step & 1;
        // ===== P1: finalize prev step (block 0) + LSTM both chains (blocks 0..127) =====
        {
            int besti = 0;
            if (step > 0) {
                unsigned long long pk = *(const unsigned long long*)&ws[OFF_AMAX];
                besti = 0x7FFFFFFF - (int)(unsigned int)(pk & 0xFFFFFFFFull);
            }
            if (step > 0 && b == 0) {
                float p = ws[OFF_XC + t] * score_w[t]
                        + ws[OFF_XC + t + 512] * score_w[t + 512];
#pragma unroll
                for (int off = 32; off; off >>= 1) p += __shfl_down(p, off);
                if (lane == 0) smem[8192 + w] = p;
                __syncthreads();
                if (t == 0) {
                    float s = 0.0f;
#pragma unroll
                    for (int ww = 0; ww < 8; ww++) s += smem[8192 + ww];
                    out[8 + NSTEP * 1024 + (step - 1)] = s + score_b[0];
                    out[step - 1] = (float)besti;
                    ws[OFF_SEL + besti] = -1e18f;
                }
                __syncthreads();
            }
            const int j = b * 8 + w;
            if (j < 1024) {
                float4 xa[4], xc[4], ha[4], hc[4];
#pragma unroll
                for (int p = 0; p < 4; p++) {
                    int kk = lane * 4 + p * 256;
                    if (step == 0) {
                        xa[p] = *(const float4*)&init_i[kk];
                        xc[p] = xa[p];
                    } else {
                        xa[p] = *(const float4*)&enc[(size_t)besti * 1024 + kk];
                        xc[p] = *(const float4*)&ws[OFF_XC + kk];
                    }
                    ha[p] = *(const float4*)&ws[OFF_H + par * 2048 + kk];
                    hc[p] = *(const float4*)&ws[OFF_H + par * 2048 + 1024 + kk];
                }
                float pa[4], pc[4];
#pragma unroll
                for (int g = 0; g < 4; g++) {
                    const float* wi = w_ih + (size_t)(g * 1024 + j) * 1024;
                    const float* wh = w_hh + (size_t)(g * 1024 + j) * 1024;
                    float sa = 0.0f, sc = 0.0f;
#pragma unroll
                    for (int p = 0; p < 4; p++) {
                        int kk = lane * 4 + p * 256;
                        float4 a = *(const float4*)&wi[kk];
                        float4 hh = *(const float4*)&wh[kk];
                        sa += a.x * xa[p].x + a.y * xa[p].y + a.z * xa[p].z + a.w * xa[p].w
                            + hh.x * ha[p].x + hh.y * ha[p].y + hh.z * ha[p].z + hh.w * ha[p].w;
                        sc += a.x * xc[p].x + a.y * xc[p].y + a.z * xc[p].z + a.w * xc[p].w
                            + hh.x * hc[p].x + hh.y * hc[p].y + hh.z * hc[p].z + hh.w * hc[p].w;
                    }
                    pa[g] = sa; pc[g] = sc;
                }
#pragma unroll
                for (int off = 1; off < 64; off <<= 1) {
#pragma unroll
                    for (int g = 0; g < 4; g++) {
                        pa[g] += __shfl_xor(pa[g], off);
                        pc[g] += __shfl_xor(pc[g], off);
                    }
                }
                if (lane == 0) {
                    float bb0 = b_ih[j] + b_hh[j];
                    float bb1 = b_ih[1024 + j] + b_hh[1024 + j];
                    float bb2 = b_ih[2048 + j] + b_hh[2048 + j];
                    float bb3 = b_ih[3072 + j] + b_hh[3072 + j];
                    {
                        float ig = sigmoidf_(pa[0] + bb0), fg = sigmoidf_(pa[1] + bb1);
                        float gg = tanhf_(pa[2] + bb2),   og = sigmoidf_(pa[3] + bb3);
                        float cv = fg * ws[OFF_C + par * 2048 + j] + ig * gg;
                        ws[OFF_H + (par ^ 1) * 2048 + j] = og * tanhf_(cv);
                        ws[OFF_C + (par ^ 1) * 2048 + j] = cv;
                    }
                    {
                        float ig = sigmoidf_(pc[0] + bb0), fg = sigmoidf_(pc[1] + bb1);
                        float gg = tanhf_(pc[2] + bb2),   og = sigmoidf_(pc[3] + bb3);
                        float cv = fg * ws[OFF_C + par * 2048 + 1024 + j] + ig * gg;
                        ws[OFF_H + (par ^ 1) * 2048 + 1024 + j] = og * tanhf_(cv);
                        ws[OFF_C + (par ^ 1) * 2048 + 1024 + j] = cv;
                    }
                }
            }
        }
        ++bt; gsync(ws, bt);

        // ===== P2: qw = h' @ hop_wq (blocks 0..63); block 64 resets AMAX =====
        if (b < 64) {
            const int chain = b >> 5, kb = b & 31;
            const float* hsrc = ws + OFF_H + (par ^ 1) * 2048 + chain * 1024;
            smem[t]       = hsrc[t];
            smem[t + 512] = hsrc[t + 512];
            __syncthreads();
            const int col = kb * 32 + (t & 31);
            const int jg = t >> 5;  // 0..15, 64 j's each
            const float* wq = hop_wq + (size_t)(jg * 64) * 1024 + col;
            float acc = 0.0f;
#pragma unroll 8
            for (int j = 0; j < 64; j++) acc += smem[jg * 64 + j] * wq[(size_t)j * 1024];
            smem[1024 + jg * 32 + (t & 31)] = acc;
            __syncthreads();
            if (t < 32) {
                float s = 0.0f;
#pragma unroll
                for (int g = 0; g < 16; g++) s += smem[1024 + g * 32 + t];
                ws[OFF_QW + chain * 1024 + kb * 32 + t] = s;
            }
        } else if (b == 64 && t == 0) {
            *(unsigned long long*)&ws[OFF_AMAX] = 0ull;
        }
        ++bt; gsync(ws, bt);

        // ===== P3: glimpse scan over hop_feat (both chains) -> per-block partials =====
        {
            float4 qa[4], qc[4], v4[4];
#pragma unroll
            for (int p = 0; p < 4; p++) {
                int kk = lane * 4 + p * 256;
                qa[p] = *(const float4*)&ws[OFF_QW + kk];
                qc[p] = *(const float4*)&ws[OFF_QW + 1024 + kk];
                v4[p] = *(const float4*)&hop_v[kk];
            }
            float la = 0.0f, lc = 0.0f;
            float4 ca[4] = {}, cc[4] = {};
            for (int i = b * 8 + w; i < NN; i += 2048) {
                const float* row = ws + OFF_HOP + (size_t)i * 1024;
                float4 f[4];
#pragma unroll
                for (int p = 0; p < 4; p++) f[p] = *(const float4*)&row[lane * 4 + p * 256];
                float sa = score16(f, qa, v4);
                float sc = score16(f, qc, v4);
#pragma unroll
                for (int off = 1; off < 64; off <<= 1) {
                    sa += __shfl_xor(sa, off);
                    sc += __shfl_xor(sc, off);
                }
                float ng = ws[OFF_NEG + i];
                float ea = __expf(sa + ng), ec = __expf(sc + ng);
                la += ea; lc += ec;
#pragma unroll
                for (int p = 0; p < 4; p++) {
                    ca[p].x += ea * f[p].x; ca[p].y += ea * f[p].y;
                    ca[p].z += ea * f[p].z; ca[p].w += ea * f[p].w;
                    cc[p].x += ec * f[p].x; cc[p].y += ec * f[p].y;
                    cc[p].z += ec * f[p].z; cc[p].w += ec * f[p].w;
                }
            }
            float* gpa = ws + OFF_GPA + (size_t)b * PSTR;
            float* gpc = ws + OFF_GPC + (size_t)b * PSTR;
            // actor
            if (lane == 0) smem[8192 + w] = la;
#pragma unroll
            for (int p = 0; p < 4; p++) *(float4*)&smem[w * 1024 + lane * 4 + p * 256] = ca[p];
            __syncthreads();
            {
                const int k = t * 2;
                float s0 = 0.0f, s1 = 0.0f;
#pragma unroll
                for (int ww = 0; ww < 8; ww++) {
                    s0 += smem[ww * 1024 + k];
                    s1 += smem[ww * 1024 + k + 1];
                }
                gpa[8 + k] = s0; gpa[8 + k + 1] = s1;
                if (t == 0) {
                    float s = 0.0f;
#pragma unroll
                    for (int ww = 0; ww < 8; ww++) s += smem[8192 + ww];
                    gpa[0] = s;
                }
            }
            __syncthreads();
            // critic
            if (lane == 0) smem[8192 + w] = lc;
#pragma unroll
            for (int p = 0; p < 4; p++) *(float4*)&smem[w * 1024 + lane * 4 + p * 256] = cc[p];
            __syncthreads();
            {
                const int k = t * 2;
                float s0 = 0.0f, s1 = 0.0f;
#pragma unroll
                for (int ww = 0; ww < 8; ww++) {
                    s0 += smem[ww * 1024 + k];
                    s1 += smem[ww * 1024 + k + 1];
                }
                gpc[8 + k] = s0; gpc[8 + k + 1] = s1;
                if (t == 0) {
                    float s = 0.0f;
#pragma unroll
                    for (int ww = 0; ww < 8; ww++) s += smem[8192 + ww];
                    gpc[0] = s;
                }
            }
            __syncthreads();
        }
        ++bt; gsync(ws, bt);

        // ===== P4: combine q = sum(ctx)/sum(l), both chains (256 blocks x 8 cols) =====
        {
            const int chain = b >> 7;
            const int base = (b & 127) * 8;
            const float* gp = ws + (chain ? OFF_GPC : OFF_GPA);
            if (t < 64) {
                float l = gp[(size_t)t * PSTR] + gp[(size_t)(t + 64) * PSTR]
                        + gp[(size_t)(t + 128) * PSTR] + gp[(size_t)(t + 192) * PSTR];
#pragma unroll
                for (int off = 1; off < 64; off <<= 1) l += __shfl_xor(l, off);
                if (t == 0) smem[600] = l;
            }
            const int col = base + (t & 7);
            const int p0 = t >> 3;
            float s = gp[(size_t)p0 * PSTR + 8 + col]
                    + gp[(size_t)(p0 + 64) * PSTR + 8 + col]
                    + gp[(size_t)(p0 + 128) * PSTR + 8 + col]
                    + gp[(size_t)(p0 + 192) * PSTR + 8 + col];
            smem[t] = s;
            __syncthreads();
            for (int off = 256; off >= 8; off >>= 1) {
                if (t < off) smem[t] += smem[t + off];
                __syncthreads();
            }
            if (t < 8) {
                float q = smem[t] / smem[600];
                ws[OFF_Q + chain * 1024 + base + t] = q;
                if (chain == 0) out[8 + step * 1024 + base + t] = q;
            }
        }
        ++bt; gsync(ws, bt);

        // ===== P5: qw2 = q @ attn_wq (blocks 0..63) =====
        if (b < 64) {
            const int chain = b >> 5, kb = b & 31;
            const float* qsrc = ws + OFF_Q + chain * 1024;
            smem[t]       = qsrc[t];
            smem[t + 512] = qsrc[t + 512];
            __syncthreads();
            const int col = kb * 32 + (t & 31);
            const int jg = t >> 5;
            const float* aw = attn_wq + (size_t)(jg * 64) * 1024 + col;
            float acc = 0.0f;
#pragma unroll 8
            for (int j = 0; j < 64; j++) acc += smem[jg * 64 + j] * aw[(size_t)j * 1024];
            smem[1024 + jg * 32 + (t & 31)] = acc;
            __syncthreads();
            if (t < 32) {
                float s = 0.0f;
#pragma unroll
                for (int g = 0; g < 16; g++) s += smem[1024 + g * 32 + t];
                ws[OFF_QW2 + chain * 1024 + kb * 32 + t] = s;
            }
        }
        ++bt; gsync(ws, bt);

        // ===== P6: attn scan — actor argmax (u64 atomicMax) + critic partials over enc =====
        {
            float4 qa[4], qc[4], v4[4];
#pragma unroll
            for (int p = 0; p < 4; p++) {
                int kk = lane * 4 + p * 256;
                qa[p] = *(const float4*)&ws[OFF_QW2 + kk];
                qc[p] = *(const float4*)&ws[OFF_QW2 + 1024 + kk];
                v4[p] = *(const float4*)&attn_v[kk];
            }
            float bm = -1e30f;
            int bi = 0;
            float lc = 0.0f;
            float4 cc[4] = {};
            for (int i = b * 8 + w; i < NN; i += 2048) {
                const float* frow = ws + OFF_ATTN + (size_t)i * 1024;
                const float* erow = enc + (size_t)i * 1024;
                float4 f[4], e[4];
#pragma unroll
                for (int p = 0; p < 4; p++) {
                    f[p] = *(const float4*)&frow[lane * 4 + p * 256];
                    e[p] = *(const float4*)&erow[lane * 4 + p * 256];
                }
                float sa = score16(f, qa, v4);
                float sc = score16(f, qc, v4);
#pragma unroll
                for (int off = 1; off < 64; off <<= 1) {
                    sa += __shfl_xor(sa, off);
                    sc += __shfl_xor(sc, off);
                }
                float ng = ws[OFF_NEG + i];
                float Sa = sa + ng + ws[OFF_SEL + i];
                if (Sa > bm) { bm = Sa; bi = i; }
                float ec = __expf(sc + ng);
                lc += ec;
#pragma unroll
                for (int p = 0; p < 4; p++) {
                    cc[p].x += ec * e[p].x; cc[p].y += ec * e[p].y;
                    cc[p].z += ec * e[p].z; cc[p].w += ec * e[p].w;
                }
            }
            unsigned long long* spk = (unsigned long long*)(smem + 8200);
            if (lane == 0) { smem[8192 + w] = lc; spk[w] = packscore(bm, bi); }
#pragma unroll
            for (int p = 0; p < 4; p++) *(float4*)&smem[w * 1024 + lane * 4 + p * 256] = cc[p];
            __syncthreads();
            float* apc = ws + OFF_APC + (size_t)b * PSTR;
            {
                const int k = t * 2;
                float s0 = 0.0f, s1 = 0.0f;
#pragma unroll
                for (int ww = 0; ww < 8; ww++) {
                    s0 += smem[ww * 1024 + k];
                    s1 += smem[ww * 1024 + k + 1];
                }
                apc[8 + k] = s0; apc[8 + k + 1] = s1;
                if (t == 0) {
                    float s = 0.0f;
                    unsigned long long mx = 0ull;
#pragma unroll
                    for (int ww = 0; ww < 8; ww++) {
                        s += smem[8192 + ww];
                        if (spk[ww] > mx) mx = spk[ww];
                    }
                    apc[0] = s;
                    atomicMax((unsigned long long*)&ws[OFF_AMAX], mx);
                }
            }
            __syncthreads();
        }
        ++bt; gsync(ws, bt);

        // ===== P7: combine critic ctx -> XC (256 blocks x 4 cols) =====
        {
            const float* ap = ws + OFF_APC;
            if (t < 64) {
                float l = ap[(size_t)t * PSTR] + ap[(size_t)(t + 64) * PSTR]
                        + ap[(size_t)(t + 128) * PSTR] + ap[(size_t)(t + 192) * PSTR];
#pragma unroll
                for (int off = 1; off < 64; off <<= 1) l += __shfl_xor(l, off);
                if (t == 0) smem[600] = l;
            }
            const int col = b * 4 + (t & 3);
            const int p0 = t >> 2;
            float s = ap[(size_t)p0 * PSTR + 8 + col]
                    + ap[(size_t)(p0 + 128) * PSTR + 8 + col];
            smem[t] = s;
            __syncthreads();
            for (int off = 256; off >= 4; off >>= 1) {
                if (t < off) smem[t] += smem[t + off];
                __syncthreads();
            }
            if (t < 4) ws[OFF_XC + b * 4 + t] = smem[t] / smem[600];
        }
        ++bt; gsync(ws, bt);
    }

    // ===== epilogue: finalize step 7 (block 0) =====
    if (b == 0) {
        unsigned long long pk = *(const unsigned long long*)&ws[OFF_AMAX];
        int besti = 0x7FFFFFFF - (int)(unsigned int)(pk & 0xFFFFFFFFull);
        float p = ws[OFF_XC + t] * score_w[t]
                + ws[OFF_XC + t + 512] * score_w[t + 512];
#pragma unroll
        for (int off = 32; off; off >>= 1) p += __shfl_down(p, off);
        if (lane == 0) smem[8192 + w] = p;
        __syncthreads();
        if (t == 0) {
            float s = 0.0f;
#pragma unroll
            for (int ww = 0; ww < 8; ww++) s += smem[8192 + ww];
            out[8 + NSTEP * 1024 + (NSTEP - 1)] = s + score_b[0];
            out[NSTEP - 1] = (float)besti;
        }
    }
}

extern "C" void kernel_launch(void* const* d_in, const int* in_sizes, int n_in,
                              void* d_out, int out_size, void* d_ws, size_t ws_size,
                              hipStream_t stream) {
    const float* enc     = (const float*)d_in[0];
    const int*   mask    = (const int*)d_in[1];
    const float* attn_wm = (const float*)d_in[2];
    const float* attn_wq = (const float*)d_in[3];
    const float* attn_v  = (const float*)d_in[4];
    const float* hop_wm  = (const float*)d_in[5];
    const float* hop_wq  = (const float*)d_in[6];
    const float* hop_v   = (const float*)d_in[7];
    const float* init_i  = (const float*)d_in[8];
    const float* init_h  = (const float*)d_in[9];
    const float* init_c  = (const float*)d_in[10];
    const float* w_ih    = (const float*)d_in[11];
    const float* w_hh    = (const float*)d_in[12];
    const float* b_ih    = (const float*)d_in[13];
    const float* b_hh    = (const float*)d_in[14];
    const float* score_w = (const float*)d_in[15];
    const float* score_b = (const float*)d_in[16];
    float* ws  = (float*)d_ws;
    float* out = (float*)d_out;

    // zero the barrier block (go/master/group counters) — graph-capturable
    (void)hipMemsetAsync((char*)d_ws + (size_t)OFF_GO * sizeof(float), 0, 8192, stream);

    k_gemm<<<dim3(8, 64, 2), 256, 0, stream>>>(enc, attn_wm, hop_wm, ws);

    k_steps<<<NBLK, NTHR, 0, stream>>>(enc, mask, attn_wq, attn_v, hop_wq, hop_v,
                                       init_h, init_c, init_i, w_ih, w_hh, b_ih,
                                       b_hh, score_w, score_b, ws, out);
}

// Round 9
// 1722.006 us; speedup vs baseline: 1.4623x; 1.2307x over previous
//
#include <hip/hip_runtime.h>
#include <hip/hip_bf16.h>

// Problem constants (reference: N=8192, D=H=1024, NSTEP=8)
#define NN 8192
#define HH 1024
#define NSTEP 8
#define NBLK 256
#define NTHR 512
#define PSTR 1040   // partial-slot stride in floats {l, pad7, ctx[1024], pad8}

// ---- workspace layout (float offsets) ----
#define OFF_ATTN   0                     // attn_feat [8192*1024]
#define OFF_HOP    8388608               // hop_feat  [8192*1024]
#define B2         16777216
#define OFF_NEG    (B2 + 0)              // [8192] write-once (atomic store, cached reads)
#define OFF_H      (B2 + 16384)          // h[parity][chain][1024]  (atomic)
#define OFF_C      (B2 + 20480)          // c[parity][chain][1024]  (atomic)
#define OFF_QW     (B2 + 24576)          // qw[chain][1024]         (atomic)
#define OFF_QW2    (B2 + 26624)          // qw2[chain][1024]        (atomic)
#define OFF_Q      (B2 + 28672)          // glimpse q [chain][1024] (atomic)
#define OFF_XC     (B2 + 30720)          // critic attn ctx [1024]  (atomic)
#define OFF_AMAX   (B2 + 31744)          // packed u64 argmax (8B aligned, atomic)
#define OFF_SELI   (B2 + 31746)          // 8 selected indices (int, atomic)
// hierarchical barrier block (zeroed via hipMemsetAsync, 8 KB)
#define OFF_GO     (B2 + 32768)          // go epoch word
#define OFF_MASTER (B2 + 32832)          // master counter
#define OFF_GRP    (B2 + 32896)          // 16 group counters, stride 64 floats
#define OFF_GPA    (B2 + 34816)          // glimpse partials actor  [256][PSTR] (atomic)
#define OFF_GPC    (OFF_GPA + 256*PSTR)  // glimpse partials critic [256][PSTR] (atomic)
#define OFF_APC    (OFF_GPC + 256*PSTR)  // attn critic partials    [256][PSTR] (atomic)

__device__ __forceinline__ float sigmoidf_(float x) {
    return 1.0f / (1.0f + __expf(-x));
}
__device__ __forceinline__ float tanhf_(float x) {
    float e = __expf(2.0f * x);
    return 1.0f - 2.0f / (e + 1.0f);
}

// agent-scope relaxed atomics: sc1 cache-bypassing ops, coherent at LLC,
// NO cache invalidation anywhere -> immutable data stays warm in L2.
__device__ __forceinline__ float aload(const float* p) {
    return __hip_atomic_load((float*)p, __ATOMIC_RELAXED, __HIP_MEMORY_SCOPE_AGENT);
}
__device__ __forceinline__ void astore(float* p, float v) {
    __hip_atomic_store(p, v, __ATOMIC_RELAXED, __HIP_MEMORY_SCOPE_AGENT);
}
__device__ __forceinline__ int aiload(const int* p) {
    return __hip_atomic_load((int*)p, __ATOMIC_RELAXED, __HIP_MEMORY_SCOPE_AGENT);
}
__device__ __forceinline__ void aistore(int* p, int v) {
    __hip_atomic_store(p, v, __ATOMIC_RELAXED, __HIP_MEMORY_SCOPE_AGENT);
}

__device__ __forceinline__ float score16(const float4* f, const float4* q, const float4* v) {
    float s = 0.0f;
#pragma unroll
    for (int j = 0; j < 4; j++) {
        s += tanhf_(f[j].x + q[j].x) * v[j].x;
        s += tanhf_(f[j].y + q[j].y) * v[j].y;
        s += tanhf_(f[j].z + q[j].z) * v[j].z;
        s += tanhf_(f[j].w + q[j].w) * v[j].w;
    }
    return s;
}

// hierarchical epoch barrier, fence-free: s_waitcnt drains this wave's bypassing
// stores (entry __syncthreads drains the others'); no buffer_inv / wbl2 ever.
__device__ __forceinline__ void gsync(float* ws, unsigned int e) {
    __syncthreads();
    if (threadIdx.x == 0) {
        unsigned int* go     = (unsigned int*)(ws + OFF_GO);
        unsigned int* master = (unsigned int*)(ws + OFF_MASTER);
        unsigned int* grp    = (unsigned int*)(ws + OFF_GRP + (blockIdx.x >> 4) * 64);
        __builtin_amdgcn_s_waitcnt(0);
        unsigned int old = __hip_atomic_fetch_add(grp, 1u, __ATOMIC_RELAXED, __HIP_MEMORY_SCOPE_AGENT);
        if (old == e * 16u - 1u) {
            unsigned int om = __hip_atomic_fetch_add(master, 1u, __ATOMIC_RELAXED, __HIP_MEMORY_SCOPE_AGENT);
            if (om == e * 16u - 1u)
                __hip_atomic_store(go, e, __ATOMIC_RELAXED, __HIP_MEMORY_SCOPE_AGENT);
        }
        while (__hip_atomic_load(go, __ATOMIC_RELAXED, __HIP_MEMORY_SCOPE_AGENT) < e)
            __builtin_amdgcn_s_sleep(8);
    }
    __syncthreads();
}

// monotone orderable key for fp32 + first-index tie-break
__device__ __forceinline__ unsigned long long packscore(float f, int i) {
    unsigned int u = __float_as_uint(f);
    unsigned int key = (u & 0x80000000u) ? ~u : (u | 0x80000000u);
    return ((unsigned long long)key << 32) | (unsigned int)(0x7FFFFFFF - i);
}

// ---------------- GEMM: feats = enc @ {attn_wm, hop_wm}, 128x128 tile, 8x8/thread ----------------
__global__ __launch_bounds__(256, 4) void k_gemm(const float* __restrict__ A,
                                                 const float* __restrict__ W0,
                                                 const float* __restrict__ W1,
                                                 float* __restrict__ ws) {
    const float* B = blockIdx.z ? W1 : W0;
    float* Cout = ws + (blockIdx.z ? OFF_HOP : OFF_ATTN);
    const int rowbase = blockIdx.y * 128;
    const int colbase = blockIdx.x * 128;
    __shared__ float As[16][132];
    __shared__ float Bs[16][132];
    const int t  = threadIdx.x;
    const int tx = t & 15;
    const int ty2 = t >> 4;  // 0..15
    const int ar = t >> 1, aks = (t & 1) * 8;
    const int bk = t >> 4, bc = (t & 15) * 8;
    float acc[8][8] = {};
    for (int kk = 0; kk < 1024; kk += 16) {
        float4 a0 = *(const float4*)&A[(size_t)(rowbase + ar) * 1024 + kk + aks];
        float4 a1 = *(const float4*)&A[(size_t)(rowbase + ar) * 1024 + kk + aks + 4];
        float4 b0 = *(const float4*)&B[(size_t)(kk + bk) * 1024 + colbase + bc];
        float4 b1 = *(const float4*)&B[(size_t)(kk + bk) * 1024 + colbase + bc + 4];
        __syncthreads();
        As[aks + 0][ar] = a0.x; As[aks + 1][ar] = a0.y;
        As[aks + 2][ar] = a0.z; As[aks + 3][ar] = a0.w;
        As[aks + 4][ar] = a1.x; As[aks + 5][ar] = a1.y;
        As[aks + 6][ar] = a1.z; As[aks + 7][ar] = a1.w;
        *(float4*)&Bs[bk][bc]     = b0;
        *(float4*)&Bs[bk][bc + 4] = b1;
        __syncthreads();
#pragma unroll
        for (int k = 0; k < 16; k++) {
            float4 x0 = *(const float4*)&As[k][ty2 * 4];
            float4 x1 = *(const float4*)&As[k][ty2 * 4 + 64];
            float4 y0 = *(const float4*)&Bs[k][tx * 4];
            float4 y1 = *(const float4*)&Bs[k][tx * 4 + 64];
            float xa[8] = {x0.x, x0.y, x0.z, x0.w, x1.x, x1.y, x1.z, x1.w};
            float yb[8] = {y0.x, y0.y, y0.z, y0.w, y1.x, y1.y, y1.z, y1.w};
#pragma unroll
            for (int i = 0; i < 8; i++)
#pragma unroll
                for (int j = 0; j < 8; j++)
                    acc[i][j] += xa[i] * yb[j];
        }
    }
#pragma unroll
    for (int i = 0; i < 8; i++) {
        int row = rowbase + ((i < 4) ? (ty2 * 4 + i) : (64 + ty2 * 4 + (i - 4)));
        float* cr = &Cout[(size_t)row * 1024 + colbase];
        *(float4*)&cr[tx * 4]      = make_float4(acc[i][0], acc[i][1], acc[i][2], acc[i][3]);
        *(float4*)&cr[64 + tx * 4] = make_float4(acc[i][4], acc[i][5], acc[i][6], acc[i][7]);
    }
}

// ---------------- persistent fused 8-step decode ----------------
__global__ __launch_bounds__(512) void k_steps(
        const float* __restrict__ enc, const int* __restrict__ mask,
        const float* __restrict__ attn_wq, const float* __restrict__ attn_v,
        const float* __restrict__ hop_wq, const float* __restrict__ hop_v,
        const float* __restrict__ init_h, const float* __restrict__ init_c,
        const float* __restrict__ init_i,
        const float* __restrict__ w_ih, const float* __restrict__ w_hh,
        const float* __restrict__ b_ih, const float* __restrict__ b_hh,
        const float* __restrict__ score_w, const float* __restrict__ score_b,
        float* __restrict__ ws, float* __restrict__ out) {
    const int b = blockIdx.x;
    const int t = threadIdx.x;
    const int w = t >> 6, lane = t & 63;
    __shared__ __align__(16) float smem[8224];
    unsigned int bt = 0;

    // ---- phase 0: init (all mutable state via bypassing stores) ----
    {
        int i = b * NTHR + t;
        if (i < NN) astore(&ws[OFF_NEG + i], (mask[i] == 0) ? -1e8f : 0.0f);
        if (i < 2048) {
            astore(&ws[OFF_H + i], init_h[i & 1023]);
            astore(&ws[OFF_C + i], init_c[i & 1023]);
        }
        if (b == 16 && t == 0) {
            astore(&ws[OFF_AMAX], 0.0f);
            astore(&ws[OFF_AMAX + 1], 0.0f);
        }
    }
    ++bt; gsync(ws, bt);

    for (int step = 0; step < NSTEP; step++) {
        const int par = step & 1;
        // ===== P1: finalize prev step (block 0) + LSTM both chains (blocks 0..127) =====
        if (b < 128) {
            int besti = 0;
            if (step > 0) {
                unsigned long long pk = __hip_atomic_load(
                    (unsigned long long*)&ws[OFF_AMAX], __ATOMIC_RELAXED, __HIP_MEMORY_SCOPE_AGENT);
                besti = 0x7FFFFFFF - (int)(unsigned int)(pk & 0xFFFFFFFFull);
            }
            if (step > 0 && b == 0) {
                float p = aload(&ws[OFF_XC + t]) * score_w[t]
                        + aload(&ws[OFF_XC + t + 512]) * score_w[t + 512];
#pragma unroll
                for (int off = 32; off; off >>= 1) p += __shfl_down(p, off);
                if (lane == 0) smem[8192 + w] = p;
                __syncthreads();
                if (t == 0) {
                    float s = 0.0f;
#pragma unroll
                    for (int ww = 0; ww < 8; ww++) s += smem[8192 + ww];
                    out[8 + NSTEP * 1024 + (step - 1)] = s + score_b[0];
                    out[step - 1] = (float)besti;
                    aistore((int*)&ws[OFF_SELI] + (step - 1), besti);
                }
                __syncthreads();
            }
            const int j = b * 8 + w;  // < 1024
            float4 xa[4], xc[4], ha[4], hc[4];
#pragma unroll
            for (int p = 0; p < 4; p++) {
                int kk = lane * 4 + p * 256;
                if (step == 0) {
                    xa[p] = *(const float4*)&init_i[kk];
                    xc[p] = xa[p];
                } else {
                    xa[p] = *(const float4*)&enc[(size_t)besti * 1024 + kk];
                    xc[p] = make_float4(aload(&ws[OFF_XC + kk]), aload(&ws[OFF_XC + kk + 1]),
                                        aload(&ws[OFF_XC + kk + 2]), aload(&ws[OFF_XC + kk + 3]));
                }
                const float* hA = ws + OFF_H + par * 2048;
                ha[p] = make_float4(aload(&hA[kk]), aload(&hA[kk + 1]),
                                    aload(&hA[kk + 2]), aload(&hA[kk + 3]));
                hc[p] = make_float4(aload(&hA[1024 + kk]), aload(&hA[1024 + kk + 1]),
                                    aload(&hA[1024 + kk + 2]), aload(&hA[1024 + kk + 3]));
            }
            float pa[4], pc[4];
#pragma unroll
            for (int g = 0; g < 4; g++) {
                const float* wi = w_ih + (size_t)(g * 1024 + j) * 1024;
                const float* wh = w_hh + (size_t)(g * 1024 + j) * 1024;
                float sa = 0.0f, sc = 0.0f;
#pragma unroll
                for (int p = 0; p < 4; p++) {
                    int kk = lane * 4 + p * 256;
                    float4 a = *(const float4*)&wi[kk];
                    float4 hh = *(const float4*)&wh[kk];
                    sa += a.x * xa[p].x + a.y * xa[p].y + a.z * xa[p].z + a.w * xa[p].w
                        + hh.x * ha[p].x + hh.y * ha[p].y + hh.z * ha[p].z + hh.w * ha[p].w;
                    sc += a.x * xc[p].x + a.y * xc[p].y + a.z * xc[p].z + a.w * xc[p].w
                        + hh.x * hc[p].x + hh.y * hc[p].y + hh.z * hc[p].z + hh.w * hc[p].w;
                }
                pa[g] = sa; pc[g] = sc;
            }
#pragma unroll
            for (int off = 1; off < 64; off <<= 1) {
#pragma unroll
                for (int g = 0; g < 4; g++) {
                    pa[g] += __shfl_xor(pa[g], off);
                    pc[g] += __shfl_xor(pc[g], off);
                }
            }
            if (lane == 0) {
                float bb0 = b_ih[j] + b_hh[j];
                float bb1 = b_ih[1024 + j] + b_hh[1024 + j];
                float bb2 = b_ih[2048 + j] + b_hh[2048 + j];
                float bb3 = b_ih[3072 + j] + b_hh[3072 + j];
                {
                    float ig = sigmoidf_(pa[0] + bb0), fg = sigmoidf_(pa[1] + bb1);
                    float gg = tanhf_(pa[2] + bb2),   og = sigmoidf_(pa[3] + bb3);
                    float cv = fg * aload(&ws[OFF_C + par * 2048 + j]) + ig * gg;
                    astore(&ws[OFF_H + (par ^ 1) * 2048 + j], og * tanhf_(cv));
                    astore(&ws[OFF_C + (par ^ 1) * 2048 + j], cv);
                }
                {
                    float ig = sigmoidf_(pc[0] + bb0), fg = sigmoidf_(pc[1] + bb1);
                    float gg = tanhf_(pc[2] + bb2),   og = sigmoidf_(pc[3] + bb3);
                    float cv = fg * aload(&ws[OFF_C + par * 2048 + 1024 + j]) + ig * gg;
                    astore(&ws[OFF_H + (par ^ 1) * 2048 + 1024 + j], og * tanhf_(cv));
                    astore(&ws[OFF_C + (par ^ 1) * 2048 + 1024 + j], cv);
                }
            }
        }
        ++bt; gsync(ws, bt);

        // ===== P2: qw = h' @ hop_wq (blocks 0..63); block 64 resets AMAX =====
        if (b < 64) {
            const int chain = b >> 5, kb = b & 31;
            const float* hsrc = ws + OFF_H + (par ^ 1) * 2048 + chain * 1024;
            smem[t]       = aload(&hsrc[t]);
            smem[t + 512] = aload(&hsrc[t + 512]);
            __syncthreads();
            const int col = kb * 32 + (t & 31);
            const int jg = t >> 5;
            const float* wq = hop_wq + (size_t)(jg * 64) * 1024 + col;
            float acc = 0.0f;
#pragma unroll 8
            for (int j = 0; j < 64; j++) acc += smem[jg * 64 + j] * wq[(size_t)j * 1024];
            smem[1024 + jg * 32 + (t & 31)] = acc;
            __syncthreads();
            if (t < 32) {
                float s = 0.0f;
#pragma unroll
                for (int g = 0; g < 16; g++) s += smem[1024 + g * 32 + t];
                astore(&ws[OFF_QW + chain * 1024 + kb * 32 + t], s);
            }
        } else if (b == 64 && t == 0) {
            astore(&ws[OFF_AMAX], 0.0f);
            astore(&ws[OFF_AMAX + 1], 0.0f);
        }
        ++bt; gsync(ws, bt);

        // ===== P3: glimpse scan over hop_feat (both chains) -> per-block partials =====
        {
            float4 qa[4], qc[4], v4[4];
#pragma unroll
            for (int p = 0; p < 4; p++) {
                int kk = lane * 4 + p * 256;
                qa[p] = make_float4(aload(&ws[OFF_QW + kk]), aload(&ws[OFF_QW + kk + 1]),
                                    aload(&ws[OFF_QW + kk + 2]), aload(&ws[OFF_QW + kk + 3]));
                qc[p] = make_float4(aload(&ws[OFF_QW + 1024 + kk]), aload(&ws[OFF_QW + 1024 + kk + 1]),
                                    aload(&ws[OFF_QW + 1024 + kk + 2]), aload(&ws[OFF_QW + 1024 + kk + 3]));
                v4[p] = *(const float4*)&hop_v[kk];
            }
            float la = 0.0f, lc = 0.0f;
            float4 ca[4] = {}, cc[4] = {};
            for (int i = b * 8 + w; i < NN; i += 2048) {
                const float* row = ws + OFF_HOP + (size_t)i * 1024;
                float4 f[4];
#pragma unroll
                for (int p = 0; p < 4; p++) f[p] = *(const float4*)&row[lane * 4 + p * 256];
                float sa = score16(f, qa, v4);
                float sc = score16(f, qc, v4);
#pragma unroll
                for (int off = 1; off < 64; off <<= 1) {
                    sa += __shfl_xor(sa, off);
                    sc += __shfl_xor(sc, off);
                }
                float ng = ws[OFF_NEG + i];  // write-once -> cached read OK
                float ea = __expf(sa + ng), ec = __expf(sc + ng);
                la += ea; lc += ec;
#pragma unroll
                for (int p = 0; p < 4; p++) {
                    ca[p].x += ea * f[p].x; ca[p].y += ea * f[p].y;
                    ca[p].z += ea * f[p].z; ca[p].w += ea * f[p].w;
                    cc[p].x += ec * f[p].x; cc[p].y += ec * f[p].y;
                    cc[p].z += ec * f[p].z; cc[p].w += ec * f[p].w;
                }
            }
            float* gpa = ws + OFF_GPA + (size_t)b * PSTR;
            float* gpc = ws + OFF_GPC + (size_t)b * PSTR;
            // actor
            if (lane == 0) smem[8192 + w] = la;
#pragma unroll
            for (int p = 0; p < 4; p++) *(float4*)&smem[w * 1024 + lane * 4 + p * 256] = ca[p];
            __syncthreads();
            {
                const int k = t * 2;
                float s0 = 0.0f, s1 = 0.0f;
#pragma unroll
                for (int ww = 0; ww < 8; ww++) {
                    s0 += smem[ww * 1024 + k];
                    s1 += smem[ww * 1024 + k + 1];
                }
                astore(&gpa[8 + k], s0);
                astore(&gpa[8 + k + 1], s1);
                if (t == 0) {
                    float s = 0.0f;
#pragma unroll
                    for (int ww = 0; ww < 8; ww++) s += smem[8192 + ww];
                    astore(&gpa[0], s);
                }
            }
            __syncthreads();
            // critic
            if (lane == 0) smem[8192 + w] = lc;
#pragma unroll
            for (int p = 0; p < 4; p++) *(float4*)&smem[w * 1024 + lane * 4 + p * 256] = cc[p];
            __syncthreads();
            {
                const int k = t * 2;
                float s0 = 0.0f, s1 = 0.0f;
#pragma unroll
                for (int ww = 0; ww < 8; ww++) {
                    s0 += smem[ww * 1024 + k];
                    s1 += smem[ww * 1024 + k + 1];
                }
                astore(&gpc[8 + k], s0);
                astore(&gpc[8 + k + 1], s1);
                if (t == 0) {
                    float s = 0.0f;
#pragma unroll
                    for (int ww = 0; ww < 8; ww++) s += smem[8192 + ww];
                    astore(&gpc[0], s);
                }
            }
            __syncthreads();
        }
        ++bt; gsync(ws, bt);

        // ===== P4: combine q = sum(ctx)/sum(l), both chains (256 blocks x 8 cols) =====
        {
            const int chain = b >> 7;
            const int base = (b & 127) * 8;
            const float* gp = ws + (chain ? OFF_GPC : OFF_GPA);
            if (t < 64) {
                float l = aload(&gp[(size_t)t * PSTR]) + aload(&gp[(size_t)(t + 64) * PSTR])
                        + aload(&gp[(size_t)(t + 128) * PSTR]) + aload(&gp[(size_t)(t + 192) * PSTR]);
#pragma unroll
                for (int off = 1; off < 64; off <<= 1) l += __shfl_xor(l, off);
                if (t == 0) smem[600] = l;
            }
            const int col = base + (t & 7);
            const int p0 = t >> 3;
            float s = aload(&gp[(size_t)p0 * PSTR + 8 + col])
                    + aload(&gp[(size_t)(p0 + 64) * PSTR + 8 + col])
                    + aload(&gp[(size_t)(p0 + 128) * PSTR + 8 + col])
                    + aload(&gp[(size_t)(p0 + 192) * PSTR + 8 + col]);
            smem[t] = s;
            __syncthreads();
            for (int off = 256; off >= 8; off >>= 1) {
                if (t < off) smem[t] += smem[t + off];
                __syncthreads();
            }
            if (t < 8) {
                float q = smem[t] / smem[600];
                astore(&ws[OFF_Q + chain * 1024 + base + t], q);
                if (chain == 0) out[8 + step * 1024 + base + t] = q;
            }
        }
        ++bt; gsync(ws, bt);

        // ===== P5: qw2 = q @ attn_wq (blocks 0..63) =====
        if (b < 64) {
            const int chain = b >> 5, kb = b & 31;
            const float* qsrc = ws + OFF_Q + chain * 1024;
            smem[t]       = aload(&qsrc[t]);
            smem[t + 512] = aload(&qsrc[t + 512]);
            __syncthreads();
            const int col = kb * 32 + (t & 31);
            const int jg = t >> 5;
            const float* aw = attn_wq + (size_t)(jg * 64) * 1024 + col;
            float acc = 0.0f;
#pragma unroll 8
            for (int j = 0; j < 64; j++) acc += smem[jg * 64 + j] * aw[(size_t)j * 1024];
            smem[1024 + jg * 32 + (t & 31)] = acc;
            __syncthreads();
            if (t < 32) {
                float s = 0.0f;
#pragma unroll
                for (int g = 0; g < 16; g++) s += smem[1024 + g * 32 + t];
                astore(&ws[OFF_QW2 + chain * 1024 + kb * 32 + t], s);
            }
        }
        ++bt; gsync(ws, bt);

        // ===== P6: attn scan — actor argmax + critic partials over enc =====
        {
            float4 qa[4], qc[4], v4[4];
#pragma unroll
            for (int p = 0; p < 4; p++) {
                int kk = lane * 4 + p * 256;
                qa[p] = make_float4(aload(&ws[OFF_QW2 + kk]), aload(&ws[OFF_QW2 + kk + 1]),
                                    aload(&ws[OFF_QW2 + kk + 2]), aload(&ws[OFF_QW2 + kk + 3]));
                qc[p] = make_float4(aload(&ws[OFF_QW2 + 1024 + kk]), aload(&ws[OFF_QW2 + 1024 + kk + 1]),
                                    aload(&ws[OFF_QW2 + 1024 + kk + 2]), aload(&ws[OFF_QW2 + 1024 + kk + 3]));
                v4[p] = *(const float4*)&attn_v[kk];
            }
            int seli[NSTEP];
            for (int s2 = 0; s2 < step; s2++) seli[s2] = aiload((int*)&ws[OFF_SELI] + s2);
            float bm = -1e30f;
            int bi = 0;
            float lc = 0.0f;
            float4 cc[4] = {};
            for (int i = b * 8 + w; i < NN; i += 2048) {
                const float* frow = ws + OFF_ATTN + (size_t)i * 1024;
                const float* erow = enc + (size_t)i * 1024;
                float4 f[4], e[4];
#pragma unroll
                for (int p = 0; p < 4; p++) {
                    f[p] = *(const float4*)&frow[lane * 4 + p * 256];
                    e[p] = *(const float4*)&erow[lane * 4 + p * 256];
                }
                float sa = score16(f, qa, v4);
                float sc = score16(f, qc, v4);
#pragma unroll
                for (int off = 1; off < 64; off <<= 1) {
                    sa += __shfl_xor(sa, off);
                    sc += __shfl_xor(sc, off);
                }
                float ng = ws[OFF_NEG + i];
                float pen = 0.0f;
                for (int s2 = 0; s2 < step; s2++) if (i == seli[s2]) pen = -1e18f;
                float Sa = sa + ng + pen;
                if (Sa > bm) { bm = Sa; bi = i; }
                float ec = __expf(sc + ng);
                lc += ec;
#pragma unroll
                for (int p = 0; p < 4; p++) {
                    cc[p].x += ec * e[p].x; cc[p].y += ec * e[p].y;
                    cc[p].z += ec * e[p].z; cc[p].w += ec * e[p].w;
                }
            }
            unsigned long long* spk = (unsigned long long*)(smem + 8200);
            if (lane == 0) { smem[8192 + w] = lc; spk[w] = packscore(bm, bi); }
#pragma unroll
            for (int p = 0; p < 4; p++) *(float4*)&smem[w * 1024 + lane * 4 + p * 256] = cc[p];
            __syncthreads();
            float* apc = ws + OFF_APC + (size_t)b * PSTR;
            {
                const int k = t * 2;
                float s0 = 0.0f, s1 = 0.0f;
#pragma unroll
                for (int ww = 0; ww < 8; ww++) {
                    s0 += smem[ww * 1024 + k];
                    s1 += smem[ww * 1024 + k + 1];
                }
                astore(&apc[8 + k], s0);
                astore(&apc[8 + k + 1], s1);
                if (t == 0) {
                    float s = 0.0f;
                    unsigned long long mx = 0ull;
#pragma unroll
                    for (int ww = 0; ww < 8; ww++) {
                        s += smem[8192 + ww];
                        if (spk[ww] > mx) mx = spk[ww];
                    }
                    astore(&apc[0], s);
                    atomicMax((unsigned long long*)&ws[OFF_AMAX], mx);
                }
            }
            __syncthreads();
        }
        ++bt; gsync(ws, bt);

        // ===== P7: combine critic ctx -> XC (256 blocks x 4 cols) =====
        {
            const float* ap = ws + OFF_APC;
            if (t < 64) {
                float l = aload(&ap[(size_t)t * PSTR]) + aload(&ap[(size_t)(t + 64) * PSTR])
                        + aload(&ap[(size_t)(t + 128) * PSTR]) + aload(&ap[(size_t)(t + 192) * PSTR]);
#pragma unroll
                for (int off = 1; off < 64; off <<= 1) l += __shfl_xor(l, off);
                if (t == 0) smem[600] = l;
            }
            const int col = b * 4 + (t & 3);
            const int p0 = t >> 2;
            float s = aload(&ap[(size_t)p0 * PSTR + 8 + col])
                    + aload(&ap[(size_t)(p0 + 128) * PSTR + 8 + col]);
            smem[t] = s;
            __syncthreads();
            for (int off = 256; off >= 4; off >>= 1) {
                if (t < off) smem[t] += smem[t + off];
                __syncthreads();
            }
            if (t < 4) astore(&ws[OFF_XC + b * 4 + t], smem[t] / smem[600]);
        }
        ++bt; gsync(ws, bt);
    }

    // ===== epilogue: finalize step 7 (block 0) =====
    if (b == 0) {
        unsigned long long pk = __hip_atomic_load(
            (unsigned long long*)&ws[OFF_AMAX], __ATOMIC_RELAXED, __HIP_MEMORY_SCOPE_AGENT);
        int besti = 0x7FFFFFFF - (int)(unsigned int)(pk & 0xFFFFFFFFull);
        float p = aload(&ws[OFF_XC + t]) * score_w[t]
                + aload(&ws[OFF_XC + t + 512]) * score_w[t + 512];
#pragma unroll
        for (int off = 32; off; off >>= 1) p += __shfl_down(p, off);
        if (lane == 0) smem[8192 + w] = p;
        __syncthreads();
        if (t == 0) {
            float s = 0.0f;
#pragma unroll
            for (int ww = 0; ww < 8; ww++) s += smem[8192 + ww];
            out[8 + NSTEP * 1024 + (NSTEP - 1)] = s + score_b[0];
            out[NSTEP - 1] = (float)besti;
        }
    }
}

extern "C" void kernel_launch(void* const* d_in, const int* in_sizes, int n_in,
                              void* d_out, int out_size, void* d_ws, size_t ws_size,
                              hipStream_t stream) {
    const float* enc     = (const float*)d_in[0];
    const int*   mask    = (const int*)d_in[1];
    const float* attn_wm = (const float*)d_in[2];
    const float* attn_wq = (const float*)d_in[3];
    const float* attn_v  = (const float*)d_in[4];
    const float* hop_wm  = (const float*)d_in[5];
    const float* hop_wq  = (const float*)d_in[6];
    const float* hop_v   = (const float*)d_in[7];
    const float* init_i  = (const float*)d_in[8];
    const float* init_h  = (const float*)d_in[9];
    const float* init_c  = (const float*)d_in[10];
    const float* w_ih    = (const float*)d_in[11];
    const float* w_hh    = (const float*)d_in[12];
    const float* b_ih    = (const float*)d_in[13];
    const float* b_hh    = (const float*)d_in[14];
    const float* score_w = (const float*)d_in[15];
    const float* score_b = (const float*)d_in[16];
    float* ws  = (float*)d_ws;
    float* out = (float*)d_out;

    // zero the barrier block (go/master/group counters) — graph-capturable
    (void)hipMemsetAsync((char*)d_ws + (size_t)OFF_GO * sizeof(float), 0, 8192, stream);

    k_gemm<<<dim3(8, 64, 2), 256, 0, stream>>>(enc, attn_wm, hop_wm, ws);

    k_steps<<<NBLK, NTHR, 0, stream>>>(enc, mask, attn_wq, attn_v, hop_wq, hop_v,
                                       init_h, init_c, init_i, w_ih, w_hh, b_ih,
                                       b_hh, score_w, score_b, ws, out);
}

// Round 10
// 1369.931 us; speedup vs baseline: 1.8381x; 1.2570x over previous
//
#include <hip/hip_runtime.h>
#include <hip/hip_bf16.h>

// Problem constants (reference: N=8192, D=H=1024, NSTEP=8)
#define NN 8192
#define HH 1024
#define NSTEP 8
#define NBLK 256
#define NTHR 512
#define PSTR 1040   // partial-slot stride in floats {l, pad7, ctx[1024], pad8}

// ---- workspace layout (float offsets) ----
#define OFF_ATTN   0                     // attn_feat [8192*1024]
#define OFF_HOP    8388608               // hop_feat  [8192*1024]
#define B2         16777216
#define OFF_NEG    (B2 + 0)              // [8192] write-once
#define OFF_H      (B2 + 16384)          // h[parity][chain][1024]  (atomic)
#define OFF_C      (B2 + 20480)          // c[parity][chain][1024]  (atomic)
#define OFF_QW     (B2 + 24576)          // qw[chain][1024]         (atomic)
#define OFF_QW2    (B2 + 26624)          // qw2[chain][1024]        (atomic)
#define OFF_Q      (B2 + 28672)          // glimpse q [chain][1024] (atomic)
#define OFF_XC     (B2 + 30720)          // critic attn ctx [1024]  (atomic)
#define OFF_AMAX   (B2 + 31744)          // packed u64 argmax
#define OFF_SELI   (B2 + 31746)          // 8 selected indices
// hierarchical barrier block (zeroed via hipMemsetAsync, 8 KB)
#define OFF_GO     (B2 + 32768)
#define OFF_MASTER (B2 + 32832)
#define OFF_GRP    (B2 + 32896)          // 16 group counters, stride 64 floats
#define OFF_GPA    (B2 + 34816)          // glimpse partials actor  [256][PSTR]
#define OFF_GPC    (OFF_GPA + 256*PSTR)  // glimpse partials critic [256][PSTR]
#define OFF_APC    (OFF_GPC + 256*PSTR)  // attn critic partials    [256][PSTR]
// bf16 transposed weight copies for GEMM — overlaps GPA region (dead until k_steps)
#define OFF_BT     OFF_GPA               // 2 matrices x (hi+lo) x 1024x1024 ushort

typedef short bshort8 __attribute__((ext_vector_type(8)));
typedef unsigned short ushortx8 __attribute__((ext_vector_type(8)));
typedef float floatx4 __attribute__((ext_vector_type(4)));

__device__ __forceinline__ float sigmoidf_(float x) {
    return 1.0f / (1.0f + __expf(-x));
}
__device__ __forceinline__ float tanhf_(float x) {
    float e = __expf(2.0f * x);
    return 1.0f - 2.0f / (e + 1.0f);
}

__device__ __forceinline__ unsigned short f2bf(float x) {
    unsigned int u = __float_as_uint(x);
    unsigned int r = (u + 0x7FFFu + ((u >> 16) & 1u)) >> 16;
    return (unsigned short)r;
}
__device__ __forceinline__ float bf2f(unsigned short h) {
    unsigned int u = ((unsigned int)h) << 16;
    return __uint_as_float(u);
}
__device__ __forceinline__ void cvt4(float4 x, unsigned short* h, unsigned short* l) {
    h[0] = f2bf(x.x); l[0] = f2bf(x.x - bf2f(h[0]));
    h[1] = f2bf(x.y); l[1] = f2bf(x.y - bf2f(h[1]));
    h[2] = f2bf(x.z); l[2] = f2bf(x.z - bf2f(h[2]));
    h[3] = f2bf(x.w); l[3] = f2bf(x.w - bf2f(h[3]));
}

// agent-scope relaxed atomics (cache-bypassing, LLC-coherent, no invalidates)
__device__ __forceinline__ float aload(const float* p) {
    return __hip_atomic_load((float*)p, __ATOMIC_RELAXED, __HIP_MEMORY_SCOPE_AGENT);
}
__device__ __forceinline__ void astore(float* p, float v) {
    __hip_atomic_store(p, v, __ATOMIC_RELAXED, __HIP_MEMORY_SCOPE_AGENT);
}
__device__ __forceinline__ int aiload(const int* p) {
    return __hip_atomic_load((int*)p, __ATOMIC_RELAXED, __HIP_MEMORY_SCOPE_AGENT);
}
__device__ __forceinline__ void aistore(int* p, int v) {
    __hip_atomic_store(p, v, __ATOMIC_RELAXED, __HIP_MEMORY_SCOPE_AGENT);
}
__device__ __forceinline__ float4 aload4(const float* p) {
    return make_float4(aload(p), aload(p + 1), aload(p + 2), aload(p + 3));
}

__device__ __forceinline__ float score16(const float4* f, const float4* q, const float4* v) {
    float s = 0.0f;
#pragma unroll
    for (int j = 0; j < 4; j++) {
        s += tanhf_(f[j].x + q[j].x) * v[j].x;
        s += tanhf_(f[j].y + q[j].y) * v[j].y;
        s += tanhf_(f[j].z + q[j].z) * v[j].z;
        s += tanhf_(f[j].w + q[j].w) * v[j].w;
    }
    return s;
}

// hierarchical epoch barrier, fence-free (see R9)
__device__ __forceinline__ void gsync(float* ws, unsigned int e) {
    __syncthreads();
    if (threadIdx.x == 0) {
        unsigned int* go     = (unsigned int*)(ws + OFF_GO);
        unsigned int* master = (unsigned int*)(ws + OFF_MASTER);
        unsigned int* grp    = (unsigned int*)(ws + OFF_GRP + (blockIdx.x >> 4) * 64);
        __builtin_amdgcn_s_waitcnt(0);
        unsigned int old = __hip_atomic_fetch_add(grp, 1u, __ATOMIC_RELAXED, __HIP_MEMORY_SCOPE_AGENT);
        if (old == e * 16u - 1u) {
            unsigned int om = __hip_atomic_fetch_add(master, 1u, __ATOMIC_RELAXED, __HIP_MEMORY_SCOPE_AGENT);
            if (om == e * 16u - 1u)
                __hip_atomic_store(go, e, __ATOMIC_RELAXED, __HIP_MEMORY_SCOPE_AGENT);
        }
        while (__hip_atomic_load(go, __ATOMIC_RELAXED, __HIP_MEMORY_SCOPE_AGENT) < e)
            __builtin_amdgcn_s_sleep(8);
    }
    __syncthreads();
}

__device__ __forceinline__ unsigned long long packscore(float f, int i) {
    unsigned int u = __float_as_uint(f);
    unsigned int key = (u & 0x80000000u) ? ~u : (u | 0x80000000u);
    return ((unsigned long long)key << 32) | (unsigned int)(0x7FFFFFFF - i);
}

// ---------------- k_cvt: wm -> transposed bf16 hi/lo pair [n][k] ----------------
__global__ __launch_bounds__(256) void k_cvt(const float* __restrict__ W0,
                                             const float* __restrict__ W1,
                                             float* __restrict__ ws) {
    const int z = blockIdx.z;
    const float* W = z ? W1 : W0;
    unsigned short* bth = (unsigned short*)(ws + OFF_BT) + (size_t)z * 2097152;
    unsigned short* btl = bth + 1048576;
    __shared__ float Ts[64][68];
    const int t = threadIdx.x;
    const int k0 = blockIdx.y * 64, n0 = blockIdx.x * 64;
    {
        const int kl = t >> 2, ns = (t & 3) * 16;
        const float* src = &W[(size_t)(k0 + kl) * 1024 + n0 + ns];
        *(float4*)&Ts[kl][ns + 0]  = *(const float4*)&src[0];
        *(float4*)&Ts[kl][ns + 4]  = *(const float4*)&src[4];
        *(float4*)&Ts[kl][ns + 8]  = *(const float4*)&src[8];
        *(float4*)&Ts[kl][ns + 12] = *(const float4*)&src[12];
    }
    __syncthreads();
    {
        const int nl = t >> 2, ks = (t & 3) * 16;
        unsigned short* dh = &bth[(size_t)(n0 + nl) * 1024 + k0 + ks];
        unsigned short* dl = &btl[(size_t)(n0 + nl) * 1024 + k0 + ks];
#pragma unroll
        for (int j = 0; j < 16; j++) {
            float x = Ts[ks + j][nl];
            unsigned short h = f2bf(x);
            dh[j] = h;
            dl[j] = f2bf(x - bf2f(h));
        }
    }
}

// ---------------- GEMM: feats = enc @ wm via split-bf16 MFMA (3-term) ----------------
// 128x128 tile, 4 waves (each 64x64 = 4x4 MFMA 16x16x32 tiles), BK=32
__global__ __launch_bounds__(256, 2) void k_gemm(const float* __restrict__ A,
                                                 float* __restrict__ ws) {
    const int z = blockIdx.z;
    const unsigned short* bth = (const unsigned short*)(ws + OFF_BT) + (size_t)z * 2097152;
    const unsigned short* btl = bth + 1048576;
    float* Cout = ws + (z ? OFF_HOP : OFF_ATTN);
    const int rowbase = blockIdx.y * 128;
    const int colbase = blockIdx.x * 128;
    __shared__ unsigned short lds[4 * 128 * 40];   // Ah, Al, Bh, Bl @ pad-40
    unsigned short* Ah = lds;
    unsigned short* Al = lds + 5120;
    unsigned short* Bh = lds + 10240;
    unsigned short* Bl = lds + 15360;
    const int t = threadIdx.x;
    const int wv = t >> 6, lane = t & 63;
    const int quad = lane >> 4, col16 = lane & 15;
    const int wrow = (wv >> 1) * 64, wcol = (wv & 1) * 64;
    const int srow = t >> 1, kseg = (t & 1) * 16;
    floatx4 acc[4][4] = {};
    for (int kk = 0; kk < 1024; kk += 32) {
        // global reads
        const float* asrc = &A[(size_t)(rowbase + srow) * 1024 + kk + kseg];
        float4 a0 = *(const float4*)&asrc[0];
        float4 a1 = *(const float4*)&asrc[4];
        float4 a2 = *(const float4*)&asrc[8];
        float4 a3 = *(const float4*)&asrc[12];
        const unsigned short* bhs = &bth[(size_t)(colbase + srow) * 1024 + kk + kseg];
        const unsigned short* bls = &btl[(size_t)(colbase + srow) * 1024 + kk + kseg];
        ushortx8 bh0 = *(const ushortx8*)&bhs[0];
        ushortx8 bh1 = *(const ushortx8*)&bhs[8];
        ushortx8 bl0 = *(const ushortx8*)&bls[0];
        ushortx8 bl1 = *(const ushortx8*)&bls[8];
        union { unsigned short u[8]; ushortx8 v; } h0, h1, l0, l1;
        cvt4(a0, h0.u, l0.u); cvt4(a1, h0.u + 4, l0.u + 4);
        cvt4(a2, h1.u, l1.u); cvt4(a3, h1.u + 4, l1.u + 4);
        __syncthreads();
        *(ushortx8*)&Ah[srow * 40 + kseg]     = h0.v;
        *(ushortx8*)&Ah[srow * 40 + kseg + 8] = h1.v;
        *(ushortx8*)&Al[srow * 40 + kseg]     = l0.v;
        *(ushortx8*)&Al[srow * 40 + kseg + 8] = l1.v;
        *(ushortx8*)&Bh[srow * 40 + kseg]     = bh0;
        *(ushortx8*)&Bh[srow * 40 + kseg + 8] = bh1;
        *(ushortx8*)&Bl[srow * 40 + kseg]     = bl0;
        *(ushortx8*)&Bl[srow * 40 + kseg + 8] = bl1;
        __syncthreads();
        bshort8 ah[4], al[4], bhf[4], blf[4];
#pragma unroll
        for (int m = 0; m < 4; m++) {
            ah[m]  = *(const bshort8*)&Ah[(wrow + m * 16 + col16) * 40 + quad * 8];
            al[m]  = *(const bshort8*)&Al[(wrow + m * 16 + col16) * 40 + quad * 8];
            bhf[m] = *(const bshort8*)&Bh[(wcol + m * 16 + col16) * 40 + quad * 8];
            blf[m] = *(const bshort8*)&Bl[(wcol + m * 16 + col16) * 40 + quad * 8];
        }
#pragma unroll
        for (int m = 0; m < 4; m++)
#pragma unroll
            for (int n = 0; n < 4; n++) {
                acc[m][n] = __builtin_amdgcn_mfma_f32_16x16x32_bf16(ah[m], bhf[n], acc[m][n], 0, 0, 0);
                acc[m][n] = __builtin_amdgcn_mfma_f32_16x16x32_bf16(ah[m], blf[n], acc[m][n], 0, 0, 0);
                acc[m][n] = __builtin_amdgcn_mfma_f32_16x16x32_bf16(al[m], bhf[n], acc[m][n], 0, 0, 0);
            }
    }
#pragma unroll
    for (int m = 0; m < 4; m++)
#pragma unroll
        for (int n = 0; n < 4; n++) {
            int r0 = rowbase + wrow + m * 16 + quad * 4;
            int c0 = colbase + wcol + n * 16 + col16;
#pragma unroll
            for (int r = 0; r < 4; r++)
                Cout[(size_t)(r0 + r) * 1024 + c0] = acc[m][n][r];
        }
}

// ---------------- persistent fused 8-step decode ----------------
__global__ __launch_bounds__(512) void k_steps(
        const float* __restrict__ enc, const int* __restrict__ mask,
        const float* __restrict__ attn_wq, const float* __restrict__ attn_v,
        const float* __restrict__ hop_wq, const float* __restrict__ hop_v,
        const float* __restrict__ init_h, const float* __restrict__ init_c,
        const float* __restrict__ init_i,
        const float* __restrict__ w_ih, const float* __restrict__ w_hh,
        const float* __restrict__ b_ih, const float* __restrict__ b_hh,
        const float* __restrict__ score_w, const float* __restrict__ score_b,
        float* __restrict__ ws, float* __restrict__ out) {
    const int b = blockIdx.x;
    const int t = threadIdx.x;
    const int w = t >> 6, lane = t & 63;
    __shared__ __align__(16) float smem[8224];
    unsigned int bt = 0;

    // ---- phase 0: init ----
    {
        int i = b * NTHR + t;
        if (i < NN) astore(&ws[OFF_NEG + i], (mask[i] == 0) ? -1e8f : 0.0f);
        if (i < 2048) {
            astore(&ws[OFF_H + i], init_h[i & 1023]);
            astore(&ws[OFF_C + i], init_c[i & 1023]);
        }
        if (b == 16 && t == 0) {
            astore(&ws[OFF_AMAX], 0.0f);
            astore(&ws[OFF_AMAX + 1], 0.0f);
        }
    }
    ++bt; gsync(ws, bt);

    for (int step = 0; step < NSTEP; step++) {
        const int par = step & 1;
        // ===== P1: finalize prev (block 0) + LSTM: all 256 blocks, 2 waves per j-row =====
        {
            int besti = 0;
            if (step > 0) {
                unsigned long long pk = __hip_atomic_load(
                    (unsigned long long*)&ws[OFF_AMAX], __ATOMIC_RELAXED, __HIP_MEMORY_SCOPE_AGENT);
                besti = 0x7FFFFFFF - (int)(unsigned int)(pk & 0xFFFFFFFFull);
            }
            if (step > 0 && b == 0) {
                float p = aload(&ws[OFF_XC + t]) * score_w[t]
                        + aload(&ws[OFF_XC + t + 512]) * score_w[t + 512];
#pragma unroll
                for (int off = 32; off; off >>= 1) p += __shfl_down(p, off);
                if (lane == 0) smem[8192 + w] = p;
                __syncthreads();
                if (t == 0) {
                    float s = 0.0f;
#pragma unroll
                    for (int ww = 0; ww < 8; ww++) s += smem[8192 + ww];
                    out[8 + NSTEP * 1024 + (step - 1)] = s + score_b[0];
                    out[step - 1] = (float)besti;
                    aistore((int*)&ws[OFF_SELI] + (step - 1), besti);
                }
                __syncthreads();
            }
            const int j  = b * 4 + (w >> 1);   // 0..1023
            const int kh = w & 1;              // k-half
            float4 xa[2], xc[2], ha[2], hc[2];
#pragma unroll
            for (int p = 0; p < 2; p++) {
                int kk = kh * 512 + lane * 4 + p * 256;
                if (step == 0) {
                    xa[p] = *(const float4*)&init_i[kk];
                    xc[p] = xa[p];
                } else {
                    xa[p] = *(const float4*)&enc[(size_t)besti * 1024 + kk];
                    xc[p] = aload4(&ws[OFF_XC + kk]);
                }
                ha[p] = aload4(&ws[OFF_H + par * 2048 + kk]);
                hc[p] = aload4(&ws[OFF_H + par * 2048 + 1024 + kk]);
            }
            float pa[4], pc[4];
#pragma unroll
            for (int g = 0; g < 4; g++) {
                const float* wi = w_ih + (size_t)(g * 1024 + j) * 1024;
                const float* wh = w_hh + (size_t)(g * 1024 + j) * 1024;
                float sa = 0.0f, sc = 0.0f;
#pragma unroll
                for (int p = 0; p < 2; p++) {
                    int kk = kh * 512 + lane * 4 + p * 256;
                    float4 a = *(const float4*)&wi[kk];
                    float4 hh = *(const float4*)&wh[kk];
                    sa += a.x * xa[p].x + a.y * xa[p].y + a.z * xa[p].z + a.w * xa[p].w
                        + hh.x * ha[p].x + hh.y * ha[p].y + hh.z * ha[p].z + hh.w * ha[p].w;
                    sc += a.x * xc[p].x + a.y * xc[p].y + a.z * xc[p].z + a.w * xc[p].w
                        + hh.x * hc[p].x + hh.y * hc[p].y + hh.z * hc[p].z + hh.w * hc[p].w;
                }
                pa[g] = sa; pc[g] = sc;
            }
#pragma unroll
            for (int off = 1; off < 64; off <<= 1) {
#pragma unroll
                for (int g = 0; g < 4; g++) {
                    pa[g] += __shfl_xor(pa[g], off);
                    pc[g] += __shfl_xor(pc[g], off);
                }
            }
            if (lane == 0) {
                const int base = (w >> 1) * 16 + kh * 8;
#pragma unroll
                for (int g = 0; g < 4; g++) {
                    smem[base + g]     = pa[g];
                    smem[base + 4 + g] = pc[g];
                }
            }
            __syncthreads();
            if (t < 8) {
                const int jl = t >> 1, chain = t & 1;
                const int j2 = b * 4 + jl;
                float v0 = smem[jl * 16 + chain * 4 + 0] + smem[jl * 16 + 8 + chain * 4 + 0];
                float v1 = smem[jl * 16 + chain * 4 + 1] + smem[jl * 16 + 8 + chain * 4 + 1];
                float v2 = smem[jl * 16 + chain * 4 + 2] + smem[jl * 16 + 8 + chain * 4 + 2];
                float v3 = smem[jl * 16 + chain * 4 + 3] + smem[jl * 16 + 8 + chain * 4 + 3];
                float bb0 = b_ih[j2] + b_hh[j2];
                float bb1 = b_ih[1024 + j2] + b_hh[1024 + j2];
                float bb2 = b_ih[2048 + j2] + b_hh[2048 + j2];
                float bb3 = b_ih[3072 + j2] + b_hh[3072 + j2];
                float ig = sigmoidf_(v0 + bb0), fg = sigmoidf_(v1 + bb1);
                float gg = tanhf_(v2 + bb2),   og = sigmoidf_(v3 + bb3);
                float cold = aload(&ws[OFF_C + par * 2048 + chain * 1024 + j2]);
                float cv = fg * cold + ig * gg;
                astore(&ws[OFF_H + (par ^ 1) * 2048 + chain * 1024 + j2], og * tanhf_(cv));
                astore(&ws[OFF_C + (par ^ 1) * 2048 + chain * 1024 + j2], cv);
            }
            __syncthreads();
        }
        ++bt; gsync(ws, bt);

        // ===== P2: qw = h' @ hop_wq (blocks 0..63); block 64 resets AMAX =====
        if (b < 64) {
            const int chain = b >> 5, kb = b & 31;
            const float* hsrc = ws + OFF_H + (par ^ 1) * 2048 + chain * 1024;
            smem[t]       = aload(&hsrc[t]);
            smem[t + 512] = aload(&hsrc[t + 512]);
            __syncthreads();
            const int col = kb * 32 + (t & 31);
            const int jg = t >> 5;
            const float* wq = hop_wq + (size_t)(jg * 64) * 1024 + col;
            float acc = 0.0f;
#pragma unroll 8
            for (int j = 0; j < 64; j++) acc += smem[jg * 64 + j] * wq[(size_t)j * 1024];
            smem[1024 + jg * 32 + (t & 31)] = acc;
            __syncthreads();
            if (t < 32) {
                float s = 0.0f;
#pragma unroll
                for (int g = 0; g < 16; g++) s += smem[1024 + g * 32 + t];
                astore(&ws[OFF_QW + chain * 1024 + kb * 32 + t], s);
            }
        } else if (b == 64 && t == 0) {
            astore(&ws[OFF_AMAX], 0.0f);
            astore(&ws[OFF_AMAX + 1], 0.0f);
        }
        ++bt; gsync(ws, bt);

        // ===== P3: glimpse scan over hop_feat, batch-4 rows (16 loads in flight) =====
        {
            float4 qa[4], qc[4], v4[4];
#pragma unroll
            for (int p = 0; p < 4; p++) {
                int kk = lane * 4 + p * 256;
                qa[p] = aload4(&ws[OFF_QW + kk]);
                qc[p] = aload4(&ws[OFF_QW + 1024 + kk]);
                v4[p] = *(const float4*)&hop_v[kk];
            }
            float la = 0.0f, lc = 0.0f;
            float4 ca[4] = {}, cc[4] = {};
            const int i0 = b * 8 + w;
            float4 f[4][4];
#pragma unroll
            for (int r = 0; r < 4; r++) {
                const float* row = ws + OFF_HOP + (size_t)(i0 + r * 2048) * 1024;
#pragma unroll
                for (int p = 0; p < 4; p++) f[r][p] = *(const float4*)&row[lane * 4 + p * 256];
            }
            float sa[4], sc[4], ng[4];
#pragma unroll
            for (int r = 0; r < 4; r++) {
                ng[r] = ws[OFF_NEG + i0 + r * 2048];
                sa[r] = score16(f[r], qa, v4);
                sc[r] = score16(f[r], qc, v4);
            }
#pragma unroll
            for (int off = 1; off < 64; off <<= 1)
#pragma unroll
                for (int r = 0; r < 4; r++) {
                    sa[r] += __shfl_xor(sa[r], off);
                    sc[r] += __shfl_xor(sc[r], off);
                }
#pragma unroll
            for (int r = 0; r < 4; r++) {
                float ea = __expf(sa[r] + ng[r]), ec = __expf(sc[r] + ng[r]);
                la += ea; lc += ec;
#pragma unroll
                for (int p = 0; p < 4; p++) {
                    ca[p].x += ea * f[r][p].x; ca[p].y += ea * f[r][p].y;
                    ca[p].z += ea * f[r][p].z; ca[p].w += ea * f[r][p].w;
                    cc[p].x += ec * f[r][p].x; cc[p].y += ec * f[r][p].y;
                    cc[p].z += ec * f[r][p].z; cc[p].w += ec * f[r][p].w;
                }
            }
            float* gpa = ws + OFF_GPA + (size_t)b * PSTR;
            float* gpc = ws + OFF_GPC + (size_t)b * PSTR;
            if (lane == 0) smem[8192 + w] = la;
#pragma unroll
            for (int p = 0; p < 4; p++) *(float4*)&smem[w * 1024 + lane * 4 + p * 256] = ca[p];
            __syncthreads();
            {
                const int k = t * 2;
                float s0 = 0.0f, s1 = 0.0f;
#pragma unroll
                for (int ww = 0; ww < 8; ww++) {
                    s0 += smem[ww * 1024 + k];
                    s1 += smem[ww * 1024 + k + 1];
                }
                astore(&gpa[8 + k], s0);
                astore(&gpa[8 + k + 1], s1);
                if (t == 0) {
                    float s = 0.0f;
#pragma unroll
                    for (int ww = 0; ww < 8; ww++) s += smem[8192 + ww];
                    astore(&gpa[0], s);
                }
            }
            __syncthreads();
            if (lane == 0) smem[8192 + w] = lc;
#pragma unroll
            for (int p = 0; p < 4; p++) *(float4*)&smem[w * 1024 + lane * 4 + p * 256] = cc[p];
            __syncthreads();
            {
                const int k = t * 2;
                float s0 = 0.0f, s1 = 0.0f;
#pragma unroll
                for (int ww = 0; ww < 8; ww++) {
                    s0 += smem[ww * 1024 + k];
                    s1 += smem[ww * 1024 + k + 1];
                }
                astore(&gpc[8 + k], s0);
                astore(&gpc[8 + k + 1], s1);
                if (t == 0) {
                    float s = 0.0f;
#pragma unroll
                    for (int ww = 0; ww < 8; ww++) s += smem[8192 + ww];
                    astore(&gpc[0], s);
                }
            }
            __syncthreads();
        }
        ++bt; gsync(ws, bt);

        // ===== P4: combine q, both chains =====
        {
            const int chain = b >> 7;
            const int base = (b & 127) * 8;
            const float* gp = ws + (chain ? OFF_GPC : OFF_GPA);
            if (t < 64) {
                float l = aload(&gp[(size_t)t * PSTR]) + aload(&gp[(size_t)(t + 64) * PSTR])
                        + aload(&gp[(size_t)(t + 128) * PSTR]) + aload(&gp[(size_t)(t + 192) * PSTR]);
#pragma unroll
                for (int off = 1; off < 64; off <<= 1) l += __shfl_xor(l, off);
                if (t == 0) smem[600] = l;
            }
            const int col = base + (t & 7);
            const int p0 = t >> 3;
            float s = aload(&gp[(size_t)p0 * PSTR + 8 + col])
                    + aload(&gp[(size_t)(p0 + 64) * PSTR + 8 + col])
                    + aload(&gp[(size_t)(p0 + 128) * PSTR + 8 + col])
                    + aload(&gp[(size_t)(p0 + 192) * PSTR + 8 + col]);
            smem[t] = s;
            __syncthreads();
            for (int off = 256; off >= 8; off >>= 1) {
                if (t < off) smem[t] += smem[t + off];
                __syncthreads();
            }
            if (t < 8) {
                float q = smem[t] / smem[600];
                astore(&ws[OFF_Q + chain * 1024 + base + t], q);
                if (chain == 0) out[8 + step * 1024 + base + t] = q;
            }
        }
        ++bt; gsync(ws, bt);

        // ===== P5: qw2 = q @ attn_wq (blocks 0..63) =====
        if (b < 64) {
            const int chain = b >> 5, kb = b & 31;
            const float* qsrc = ws + OFF_Q + chain * 1024;
            smem[t]       = aload(&qsrc[t]);
            smem[t + 512] = aload(&qsrc[t + 512]);
            __syncthreads();
            const int col = kb * 32 + (t & 31);
            const int jg = t >> 5;
            const float* aw = attn_wq + (size_t)(jg * 64) * 1024 + col;
            float acc = 0.0f;
#pragma unroll 8
            for (int j = 0; j < 64; j++) acc += smem[jg * 64 + j] * aw[(size_t)j * 1024];
            smem[1024 + jg * 32 + (t & 31)] = acc;
            __syncthreads();
            if (t < 32) {
                float s = 0.0f;
#pragma unroll
                for (int g = 0; g < 16; g++) s += smem[1024 + g * 32 + t];
                astore(&ws[OFF_QW2 + chain * 1024 + kb * 32 + t], s);
            }
        }
        ++bt; gsync(ws, bt);

        // ===== P6: attn scan, batch-2 rows — actor argmax + critic partials over enc =====
        {
            float4 qa[4], qc[4], v4[4];
#pragma unroll
            for (int p = 0; p < 4; p++) {
                int kk = lane * 4 + p * 256;
                qa[p] = aload4(&ws[OFF_QW2 + kk]);
                qc[p] = aload4(&ws[OFF_QW2 + 1024 + kk]);
                v4[p] = *(const float4*)&attn_v[kk];
            }
            int seli[NSTEP];
            for (int s2 = 0; s2 < step; s2++) seli[s2] = aiload((int*)&ws[OFF_SELI] + s2);
            float bm = -1e30f;
            int bi = 0;
            float lc = 0.0f;
            float4 cc[4] = {};
            const int i0 = b * 8 + w;
#pragma unroll
            for (int rr = 0; rr < 2; rr++) {
                const int ia = i0 + rr * 4096;
                const int ib = ia + 2048;
                float4 f[2][4], e[2][4];
                {
                    const float* fr0 = ws + OFF_ATTN + (size_t)ia * 1024;
                    const float* er0 = enc + (size_t)ia * 1024;
                    const float* fr1 = ws + OFF_ATTN + (size_t)ib * 1024;
                    const float* er1 = enc + (size_t)ib * 1024;
#pragma unroll
                    for (int p = 0; p < 4; p++) {
                        f[0][p] = *(const float4*)&fr0[lane * 4 + p * 256];
                        e[0][p] = *(const float4*)&er0[lane * 4 + p * 256];
                        f[1][p] = *(const float4*)&fr1[lane * 4 + p * 256];
                        e[1][p] = *(const float4*)&er1[lane * 4 + p * 256];
                    }
                }
                float ng0 = ws[OFF_NEG + ia], ng1 = ws[OFF_NEG + ib];
                float sa0 = score16(f[0], qa, v4), sc0 = score16(f[0], qc, v4);
                float sa1 = score16(f[1], qa, v4), sc1 = score16(f[1], qc, v4);
#pragma unroll
                for (int off = 1; off < 64; off <<= 1) {
                    sa0 += __shfl_xor(sa0, off); sc0 += __shfl_xor(sc0, off);
                    sa1 += __shfl_xor(sa1, off); sc1 += __shfl_xor(sc1, off);
                }
                float pen0 = 0.0f, pen1 = 0.0f;
                for (int s2 = 0; s2 < step; s2++) {
                    if (ia == seli[s2]) pen0 = -1e18f;
                    if (ib == seli[s2]) pen1 = -1e18f;
                }
                float Sa0 = sa0 + ng0 + pen0;
                if (Sa0 > bm) { bm = Sa0; bi = ia; }
                float Sa1 = sa1 + ng1 + pen1;
                if (Sa1 > bm) { bm = Sa1; bi = ib; }
                float ec0 = __expf(sc0 + ng0), ec1 = __expf(sc1 + ng1);
                lc += ec0 + ec1;
#pragma unroll
                for (int p = 0; p < 4; p++) {
                    cc[p].x += ec0 * e[0][p].x + ec1 * e[1][p].x;
                    cc[p].y += ec0 * e[0][p].y + ec1 * e[1][p].y;
                    cc[p].z += ec0 * e[0][p].z + ec1 * e[1][p].z;
                    cc[p].w += ec0 * e[0][p].w + ec1 * e[1][p].w;
                }
            }
            unsigned long long* spk = (unsigned long long*)(smem + 8200);
            if (lane == 0) { smem[8192 + w] = lc; spk[w] = packscore(bm, bi); }
#pragma unroll
            for (int p = 0; p < 4; p++) *(float4*)&smem[w * 1024 + lane * 4 + p * 256] = cc[p];
            __syncthreads();
            float* apc = ws + OFF_APC + (size_t)b * PSTR;
            {
                const int k = t * 2;
                float s0 = 0.0f, s1 = 0.0f;
#pragma unroll
                for (int ww = 0; ww < 8; ww++) {
                    s0 += smem[ww * 1024 + k];
                    s1 += smem[ww * 1024 + k + 1];
                }
                astore(&apc[8 + k], s0);
                astore(&apc[8 + k + 1], s1);
                if (t == 0) {
                    float s = 0.0f;
                    unsigned long long mx = 0ull;
#pragma unroll
                    for (int ww = 0; ww < 8; ww++) {
                        s += smem[8192 + ww];
                        if (spk[ww] > mx) mx = spk[ww];
                    }
                    astore(&apc[0], s);
                    atomicMax((unsigned long long*)&ws[OFF_AMAX], mx);
                }
            }
            __syncthreads();
        }
        ++bt; gsync(ws, bt);

        // ===== P7: combine critic ctx -> XC =====
        {
            const float* ap = ws + OFF_APC;
            if (t < 64) {
                float l = aload(&ap[(size_t)t * PSTR]) + aload(&ap[(size_t)(t + 64) * PSTR])
                        + aload(&ap[(size_t)(t + 128) * PSTR]) + aload(&ap[(size_t)(t + 192) * PSTR]);
#pragma unroll
                for (int off = 1; off < 64; off <<= 1) l += __shfl_xor(l, off);
                if (t == 0) smem[600] = l;
            }
            const int col = b * 4 + (t & 3);
            const int p0 = t >> 2;
            float s = aload(&ap[(size_t)p0 * PSTR + 8 + col])
                    + aload(&ap[(size_t)(p0 + 128) * PSTR + 8 + col]);
            smem[t] = s;
            __syncthreads();
            for (int off = 256; off >= 4; off >>= 1) {
                if (t < off) smem[t] += smem[t + off];
                __syncthreads();
            }
            if (t < 4) astore(&ws[OFF_XC + b * 4 + t], smem[t] / smem[600]);
        }
        ++bt; gsync(ws, bt);
    }

    // ===== epilogue: finalize step 7 (block 0) =====
    if (b == 0) {
        unsigned long long pk = __hip_atomic_load(
            (unsigned long long*)&ws[OFF_AMAX], __ATOMIC_RELAXED, __HIP_MEMORY_SCOPE_AGENT);
        int besti = 0x7FFFFFFF - (int)(unsigned int)(pk & 0xFFFFFFFFull);
        float p = aload(&ws[OFF_XC + t]) * score_w[t]
                + aload(&ws[OFF_XC + t + 512]) * score_w[t + 512];
#pragma unroll
        for (int off = 32; off; off >>= 1) p += __shfl_down(p, off);
        if (lane == 0) smem[8192 + w] = p;
        __syncthreads();
        if (t == 0) {
            float s = 0.0f;
#pragma unroll
            for (int ww = 0; ww < 8; ww++) s += smem[8192 + ww];
            out[8 + NSTEP * 1024 + (NSTEP - 1)] = s + score_b[0];
            out[NSTEP - 1] = (float)besti;
        }
    }
}

extern "C" void kernel_launch(void* const* d_in, const int* in_sizes, int n_in,
                              void* d_out, int out_size, void* d_ws, size_t ws_size,
                              hipStream_t stream) {
    const float* enc     = (const float*)d_in[0];
    const int*   mask    = (const int*)d_in[1];
    const float* attn_wm = (const float*)d_in[2];
    const float* attn_wq = (const float*)d_in[3];
    const float* attn_v  = (const float*)d_in[4];
    const float* hop_wm  = (const float*)d_in[5];
    const float* hop_wq  = (const float*)d_in[6];
    const float* hop_v   = (const float*)d_in[7];
    const float* init_i  = (const float*)d_in[8];
    const float* init_h  = (const float*)d_in[9];
    const float* init_c  = (const float*)d_in[10];
    const float* w_ih    = (const float*)d_in[11];
    const float* w_hh    = (const float*)d_in[12];
    const float* b_ih    = (const float*)d_in[13];
    const float* b_hh    = (const float*)d_in[14];
    const float* score_w = (const float*)d_in[15];
    const float* score_b = (const float*)d_in[16];
    float* ws  = (float*)d_ws;
    float* out = (float*)d_out;

    (void)hipMemsetAsync((char*)d_ws + (size_t)OFF_GO * sizeof(float), 0, 8192, stream);

    k_cvt<<<dim3(16, 16, 2), 256, 0, stream>>>(attn_wm, hop_wm, ws);
    k_gemm<<<dim3(8, 64, 2), 256, 0, stream>>>(enc, ws);

    k_steps<<<NBLK, NTHR, 0, stream>>>(enc, mask, attn_wq, attn_v, hop_wq, hop_v,
                                       init_h, init_c, init_i, w_ih, w_hh, b_ih,
                                       b_hh, score_w, score_b, ws, out);
}